// Round 11
// baseline (634.637 us; speedup 1.0000x reference)
//
#include <hip/hip_runtime.h>
#include <hip/hip_bf16.h>

#define SEQ 2048
#define HID 4096
#define NHEADS 32
#define HDIM 128
#define LR 8

typedef __attribute__((ext_vector_type(8))) short bf16x8;
typedef __attribute__((ext_vector_type(4))) float f32x4;
typedef __attribute__((ext_vector_type(16))) float f32x16;

typedef __attribute__((address_space(3))) void lds_void;
typedef const __attribute__((address_space(1))) void glb_void;

static __device__ __forceinline__ float bf2f(__hip_bfloat16 v) { return __bfloat162float(v); }
static __device__ __forceinline__ __hip_bfloat16 f2bf(float v) { return __float2bfloat16(v); }

static __device__ __forceinline__ unsigned pkbf(float lo, float hi2) {
  __hip_bfloat16 l = __float2bfloat16(lo), h2 = __float2bfloat16(hi2);
  unsigned short ul = *reinterpret_cast<unsigned short*>(&l);
  unsigned short uh = *reinterpret_cast<unsigned short*>(&h2);
  return ((unsigned)uh << 16) | ul;
}

// ---------------------------------------------------------------- fp32 -> bf16
__global__ __launch_bounds__(256) void conv_f32_bf16(const float* __restrict__ src,
                                                     __hip_bfloat16* __restrict__ dst,
                                                     int n4) {
  const int i = blockIdx.x * 256 + threadIdx.x;
  if (i >= n4) return;
  const float4 v = reinterpret_cast<const float4*>(src)[i];
  union { __hip_bfloat16 h[4]; ushort4 u; } pk;
  pk.h[0] = f2bf(v.x); pk.h[1] = f2bf(v.y); pk.h[2] = f2bf(v.z); pk.h[3] = f2bf(v.w);
  reinterpret_cast<ushort4*>(dst)[i] = pk.u;
}

// ---------------------------------------------------------------- t = x @ A^T  (fp32, rank 8)
__global__ __launch_bounds__(256) void lora_t(const float* __restrict__ x,
                                              const float* __restrict__ Aq,
                                              const float* __restrict__ Ak,
                                              const float* __restrict__ Av,
                                              float* __restrict__ tq,
                                              float* __restrict__ tk,
                                              float* __restrict__ tv) {
  const int gw = blockIdx.x * 4 + (threadIdx.x >> 6);
  const int lane = threadIdx.x & 63;
  const int which = gw / SEQ;
  const int s = gw - which * SEQ;
  const float* A = (which == 0) ? Aq : (which == 1) ? Ak : Av;
  float* t = (which == 0) ? tq : (which == 1) ? tk : tv;
  float acc[LR];
#pragma unroll
  for (int r = 0; r < LR; ++r) acc[r] = 0.0f;
  const float4* xr = reinterpret_cast<const float4*>(x + (size_t)s * HID);
  for (int c = lane; c < HID / 4; c += 64) {
    const float4 xv = xr[c];
#pragma unroll
    for (int r = 0; r < LR; ++r) {
      const float4 av = reinterpret_cast<const float4*>(A + r * HID)[c];
      acc[r] += xv.x * av.x + xv.y * av.y + xv.z * av.z + xv.w * av.w;
    }
  }
#pragma unroll
  for (int r = 0; r < LR; ++r) {
    float vv = acc[r];
#pragma unroll
    for (int off = 32; off > 0; off >>= 1) vv += __shfl_down(vv, off);
    if (lane == 0) t[s * LR + r] = vv;
  }
}

// ---------------------------------------------------------------- RoPE cos/sin tables [S][64]
__global__ __launch_bounds__(256) void rope_tables(float* __restrict__ cosb,
                                                   float* __restrict__ sinb) {
  const int i = blockIdx.x * 256 + threadIdx.x;
  const int s = i >> 6, d = i & 63;
  const float invf = powf(10000.0f, -(float)d * (1.0f / 64.0f));
  const float ang = (float)s * invf;
  cosb[i] = cosf(ang);
  sinb[i] = sinf(ang);
}

// ---------------------------------------------------------------- RoPE in-place on bf16 (S,4096)
__global__ __launch_bounds__(256) void rope_apply(__hip_bfloat16* __restrict__ t,
                                                  const float* __restrict__ cosb,
                                                  const float* __restrict__ sinb) {
  const int i = blockIdx.x * 256 + threadIdx.x;
  const int d = i & 63;
  const int hh = (i >> 6) & (NHEADS - 1);
  const int s = i >> 11;
  const size_t base = (size_t)s * HID + hh * HDIM;
  const float x1 = bf2f(t[base + d]);
  const float x2 = bf2f(t[base + d + 64]);
  const float cc = cosb[s * 64 + d];
  const float ss = sinb[s * 64 + d];
  t[base + d] = f2bf(x1 * cc - x2 * ss);
  t[base + d + 64] = f2bf(x1 * ss + x2 * cc);
}

// ---------------------------------------------------------------- V (S,4096) -> Vt [h][d][s]
__global__ __launch_bounds__(256) void transpose_v(const __hip_bfloat16* __restrict__ v,
                                                   __hip_bfloat16* __restrict__ vt) {
  __shared__ __hip_bfloat16 tile[64][72];
  const int h = blockIdx.z;
  const int s0 = blockIdx.x * 64;
  const int db = blockIdx.y * 64;
  const int c = (threadIdx.x & 7) * 8;
  const int r = threadIdx.x >> 3;
#pragma unroll
  for (int p = 0; p < 2; ++p) {
    const int rr = r + p * 32;
    *reinterpret_cast<float4*>(&tile[rr][c]) =
        *reinterpret_cast<const float4*>(v + (size_t)(s0 + rr) * HID + h * HDIM + db + c);
  }
  __syncthreads();
#pragma unroll
  for (int p = 0; p < 2; ++p) {
    const int rr = r + p * 32;
    alignas(16) __hip_bfloat16 tmp[8];
#pragma unroll
    for (int j = 0; j < 8; ++j) tmp[j] = tile[c + j][rr];
    *reinterpret_cast<float4*>(vt + (size_t)(h * HDIM + db + rr) * SEQ + s0 + c) =
        *reinterpret_cast<float4*>(tmp);
  }
}

// ---------------------------------------------------------------- QKV GEMM v8: phase-split schedule
// BM=BN=256, BK=64, 8 waves; wave-tile 128x64 (8x4 frags) -> 24 ds_read / 64 MFMA.
// 4 phases per K-tile: (kh0,m0)(kh0,m1)(kh1,m0)(kh1,m1). Phase = entry-sync ->
// ds_read subtile -> stage ONE region of tile j+1 -> lgkmcnt(0) -> setprio(1) ->
// 16 MFMA -> setprio(0). Counted vmcnt ONLY at kh-entry phases (m201 cadence):
// region issue order per tile [Akh0,Bkh0,Akh1,Bkh1] (2 loads each); entering a kh,
// outstanding=8, vmcnt(4) retires exactly the A+B regions of that kh. B-frags
// persist in regs across the two M-phases of a kh. Staging/swizzle math verbatim
// from R9 (refcheck'd); read math verbatim from R7 (refcheck'd).
__global__ __launch_bounds__(512, 2) void gemm8(const __hip_bfloat16* __restrict__ X,
                                                const __hip_bfloat16* __restrict__ wqkv,
                                                const float* __restrict__ tq,
                                                const float* __restrict__ tk,
                                                const float* __restrict__ tv,
                                                const float* __restrict__ Bq,
                                                const float* __restrict__ Bk,
                                                const float* __restrict__ Bv,
                                                __hip_bfloat16* __restrict__ qb,
                                                __hip_bfloat16* __restrict__ kb,
                                                __hip_bfloat16* __restrict__ vb) {
  __shared__ __hip_bfloat16 Al[2][2][256][32];  // 64 KB
  __shared__ __hip_bfloat16 Bl[2][2][256][32];  // 64 KB
  const int z = blockIdx.z;
  const __hip_bfloat16* W = wqkv + (size_t)z * HID * HID;
  const float* T = (z == 0) ? tq : (z == 1) ? tk : tv;
  const float* BL = (z == 0) ? Bq : (z == 1) ? Bk : Bv;
  __hip_bfloat16* outb = (z == 0) ? qb : (z == 1) ? kb : vb;

  const int tid = threadIdx.x;
  const int lane = tid & 63;
  const int w = tid >> 6;   // 0..7
  const int wm2 = w >> 2;   // M half (128 rows)
  const int wn4 = w & 3;    // N quarter (64 cols)
  const int g = lane >> 4, lr = lane & 15;

  // XCD col-panel swizzle: xcd = fid&7 owns col panels {2x,2x+1} (L2-resident W)
  const int fid = blockIdx.x + (blockIdx.y << 4);  // 0..127
  const int rowBase = (fid >> 4) * 256;            // 0..7
  const int colBase = ((fid & 7) * 2 + ((fid >> 3) & 1)) * 256;  // 0..15

  // staging: per region (operand, kh) = 256x32 bf16 = 1024 16B slots, 2/thread
  const int s0 = (w * 2) * 64 + lane;
  const int s1 = s0 + 64;
  const int r0 = s0 >> 2, c0 = s0 & 3;
  const int r1 = s1 >> 2, c1 = s1 & 3;
  const __hip_bfloat16* Ag0 = X + (size_t)(rowBase + r0) * HID + ((c0 ^ ((r0 >> 1) & 3)) * 8);
  const __hip_bfloat16* Ag1 = X + (size_t)(rowBase + r1) * HID + ((c1 ^ ((r1 >> 1) & 3)) * 8);
  const __hip_bfloat16* Bg0 = W + (size_t)(colBase + r0) * HID + ((c0 ^ ((r0 >> 1) & 3)) * 8);
  const __hip_bfloat16* Bg1 = W + (size_t)(colBase + r1) * HID + ((c1 ^ ((r1 >> 1) & 3)) * 8);

#define SGA(buf_, kh_, kk_)                                                         \
  do {                                                                              \
    __builtin_amdgcn_global_load_lds((glb_void*)(Ag0 + (kk_) + (kh_) * 32),         \
        (lds_void*)(&Al[buf_][kh_][0][0] + (w * 2) * 512), 16, 0, 0);               \
    __builtin_amdgcn_global_load_lds((glb_void*)(Ag1 + (kk_) + (kh_) * 32),         \
        (lds_void*)(&Al[buf_][kh_][0][0] + (w * 2 + 1) * 512), 16, 0, 0);           \
  } while (0)
#define SGB(buf_, kh_, kk_)                                                         \
  do {                                                                              \
    __builtin_amdgcn_global_load_lds((glb_void*)(Bg0 + (kk_) + (kh_) * 32),         \
        (lds_void*)(&Bl[buf_][kh_][0][0] + (w * 2) * 512), 16, 0, 0);               \
    __builtin_amdgcn_global_load_lds((glb_void*)(Bg1 + (kk_) + (kh_) * 32),         \
        (lds_void*)(&Bl[buf_][kh_][0][0] + (w * 2 + 1) * 512), 16, 0, 0);           \
  } while (0)

  f32x4 acc[8][4];
#pragma unroll
  for (int m = 0; m < 8; ++m)
#pragma unroll
    for (int n = 0; n < 4; ++n)
#pragma unroll
      for (int e = 0; e < 4; ++e) acc[m][n][e] = 0.0f;

  const int ch = (g ^ ((lr >> 1) & 3)) * 8;

  // prologue: tile 0 regions in FIFO order [A-kh0, B-kh0, A-kh1, B-kh1] = 8 loads
  SGA(0, 0, 0);
  __builtin_amdgcn_sched_barrier(0);
  SGB(0, 0, 0);
  __builtin_amdgcn_sched_barrier(0);
  SGA(0, 1, 0);
  __builtin_amdgcn_sched_barrier(0);
  SGB(0, 1, 0);

  for (int j = 0; j < 64; ++j) {
    const int cur = j & 1, nxt = cur ^ 1;
    const int kn = (j < 63 ? j + 1 : 63) * 64;  // tail: redundant re-stage keeps FIFO
    bf16x8 bf[4];
#pragma unroll
    for (int kh = 0; kh < 2; ++kh) {
#pragma unroll
      for (int mh = 0; mh < 2; ++mh) {
        if (mh == 0) asm volatile("s_waitcnt vmcnt(4)" ::: "memory");
        __builtin_amdgcn_s_barrier();
        __builtin_amdgcn_sched_barrier(0);
        bf16x8 af[4];
#pragma unroll
        for (int mf = 0; mf < 4; ++mf)
          af[mf] = *reinterpret_cast<const bf16x8*>(
              &Al[cur][kh][wm2 * 128 + mh * 64 + mf * 16 + lr][ch]);
        if (mh == 0) {
#pragma unroll
          for (int nf = 0; nf < 4; ++nf)
            bf[nf] = *reinterpret_cast<const bf16x8*>(
                &Bl[cur][kh][wn4 * 64 + nf * 16 + lr][ch]);
        }
        // stage region (kh,mh) of next tile: A at mh==0, B at mh==1
        if (kh == 0) { if (mh == 0) SGA(nxt, 0, kn); else SGB(nxt, 0, kn); }
        else         { if (mh == 0) SGA(nxt, 1, kn); else SGB(nxt, 1, kn); }
        __builtin_amdgcn_sched_barrier(0);
        asm volatile("s_waitcnt lgkmcnt(0)" ::: "memory");
        __builtin_amdgcn_sched_barrier(0);
        __builtin_amdgcn_s_setprio(1);
#pragma unroll
        for (int mf = 0; mf < 4; ++mf)
#pragma unroll
          for (int nf = 0; nf < 4; ++nf)
            acc[mh * 4 + mf][nf] =
                __builtin_amdgcn_mfma_f32_16x16x32_bf16(af[mf], bf[nf], acc[mh * 4 + mf][nf], 0, 0, 0);
        __builtin_amdgcn_s_setprio(0);
      }
    }
  }
#undef SGA
#undef SGB

  // epilogue: LoRA + bf16 store. acc[mi][nf]: row = rowBase + wm2*128 + (mi>>2)*64
  // + (mi&3)*16 + g*4 + r2 ; col = colBase + wn4*64 + nf*16 + lr.
#pragma unroll
  for (int mi = 0; mi < 8; ++mi) {
    const int orow0 = rowBase + wm2 * 128 + (mi >> 2) * 64 + (mi & 3) * 16 + g * 4;
    float tr[4][8];
#pragma unroll
    for (int r2 = 0; r2 < 4; ++r2)
#pragma unroll
      for (int e = 0; e < 8; ++e) tr[r2][e] = T[(size_t)(orow0 + r2) * LR + e];
#pragma unroll
    for (int nf = 0; nf < 4; ++nf) {
      const int cc = colBase + wn4 * 64 + nf * 16 + lr;
      const int fc = (cc < HID / 2) ? (2 * cc) : (2 * (cc - HID / 2) + 1);
      float bl[8];
#pragma unroll
      for (int e = 0; e < 8; ++e) bl[e] = BL[fc * LR + e];
#pragma unroll
      for (int r2 = 0; r2 < 4; ++r2) {
        float dot = 0.0f;
#pragma unroll
        for (int e = 0; e < 8; ++e) dot += tr[r2][e] * bl[e];
        outb[(size_t)(orow0 + r2) * HID + cc] = f2bf(acc[mi][nf][r2] + 2.0f * dot);
      }
    }
  }
}

// ---------------------------------------------------------------- Wo GEMM (proven counted-vmcnt, 3-buffer)
template <bool LORA>
__global__ __launch_bounds__(512, 2) void gemm2(const __hip_bfloat16* __restrict__ X,
                                                const __hip_bfloat16* __restrict__ wqkv,
                                                const float* __restrict__ tq,
                                                const float* __restrict__ tk,
                                                const float* __restrict__ tv,
                                                const float* __restrict__ Bq,
                                                const float* __restrict__ Bk,
                                                const float* __restrict__ Bv,
                                                __hip_bfloat16* __restrict__ qb,
                                                __hip_bfloat16* __restrict__ kb,
                                                __hip_bfloat16* __restrict__ vb,
                                                float* __restrict__ outf) {
  __shared__ __hip_bfloat16 Al[3][2][128][32];
  __shared__ __hip_bfloat16 Bl[3][2][256][32];
  const int z = blockIdx.z;
  const __hip_bfloat16* W = wqkv + (size_t)z * HID * HID;
  const float* T = (z == 0) ? tq : (z == 1) ? tk : tv;
  const float* BL = (z == 0) ? Bq : (z == 1) ? Bk : Bv;
  __hip_bfloat16* outb = (z == 0) ? qb : (z == 1) ? kb : vb;

  const int tid = threadIdx.x;
  const int lane = tid & 63;
  const int w = tid >> 6;
  const int wm = w >> 2;
  const int wn = w & 3;
  const int g = lane >> 4, lr = lane & 15;

  const int fid = blockIdx.x + (blockIdx.y << 4);
  const int xcd = fid & 7;
  const int j8 = fid >> 3;
  const int rowBase = (j8 >> 1) * 128;
  const int colBase = (xcd * 2 + (j8 & 1)) * 256;

  const int sA = w * 64 + lane;
  const int rA = sA >> 2, cA = sA & 3;
  const __hip_bfloat16* Ag = X + (size_t)(rowBase + rA) * HID + ((cA ^ ((rA >> 1) & 3)) * 8);
  const int sB0 = (w * 2) * 64 + lane;
  const int sB1 = (w * 2 + 1) * 64 + lane;
  const int rB0 = sB0 >> 2, cB0 = sB0 & 3;
  const int rB1 = sB1 >> 2, cB1 = sB1 & 3;
  const __hip_bfloat16* Bg0 = W + (size_t)(colBase + rB0) * HID + ((cB0 ^ ((rB0 >> 1) & 3)) * 8);
  const __hip_bfloat16* Bg1 = W + (size_t)(colBase + rB1) * HID + ((cB1 ^ ((rB1 >> 1) & 3)) * 8);

#define STG2(buf_, kh_, kk_)                                                        \
  do {                                                                              \
    __builtin_amdgcn_global_load_lds((glb_void*)(Ag + (kk_) + (kh_) * 32),          \
        (lds_void*)(&Al[buf_][kh_][0][0] + w * 512), 16, 0, 0);                     \
    __builtin_amdgcn_global_load_lds((glb_void*)(Bg0 + (kk_) + (kh_) * 32),         \
        (lds_void*)(&Bl[buf_][kh_][0][0] + (w * 2) * 512), 16, 0, 0);               \
    __builtin_amdgcn_global_load_lds((glb_void*)(Bg1 + (kk_) + (kh_) * 32),         \
        (lds_void*)(&Bl[buf_][kh_][0][0] + (w * 2 + 1) * 512), 16, 0, 0);           \
  } while (0)

  f32x4 acc[4][4];
#pragma unroll
  for (int m = 0; m < 4; ++m)
#pragma unroll
    for (int n = 0; n < 4; ++n)
#pragma unroll
      for (int e = 0; e < 4; ++e) acc[m][n][e] = 0.0f;

  const int ch = (g ^ ((lr >> 1) & 3)) * 8;

  STG2(0, 0, 0);
  __builtin_amdgcn_sched_barrier(0);
  STG2(0, 1, 0);
  __builtin_amdgcn_sched_barrier(0);
  STG2(1, 0, 64);
  __builtin_amdgcn_sched_barrier(0);
  STG2(1, 1, 64);

  int bcur = 0;
  for (int j = 0; j < 64; ++j) {
    int bn2 = bcur + 2; if (bn2 >= 3) bn2 -= 3;
    const int kn = (j < 62 ? j + 2 : 63) * 64;
#pragma unroll
    for (int kh = 0; kh < 2; ++kh) {
      asm volatile("s_waitcnt vmcnt(9) lgkmcnt(0)" ::: "memory");
      __builtin_amdgcn_s_barrier();
      __builtin_amdgcn_sched_barrier(0);
      bf16x8 af[4], bfr[4];
#pragma unroll
      for (int m = 0; m < 4; ++m)
        af[m] = *reinterpret_cast<const bf16x8*>(&Al[bcur][kh][wm * 64 + m * 16 + lr][ch]);
#pragma unroll
      for (int n = 0; n < 4; ++n)
        bfr[n] = *reinterpret_cast<const bf16x8*>(&Bl[bcur][kh][wn * 64 + n * 16 + lr][ch]);
      if (kh == 0) STG2(bn2, 0, kn); else STG2(bn2, 1, kn);
      __builtin_amdgcn_sched_barrier(0);
      __builtin_amdgcn_s_setprio(1);
#pragma unroll
      for (int m = 0; m < 4; ++m)
#pragma unroll
        for (int n = 0; n < 4; ++n)
          acc[m][n] = __builtin_amdgcn_mfma_f32_16x16x32_bf16(af[m], bfr[n], acc[m][n], 0, 0, 0);
      __builtin_amdgcn_s_setprio(0);
    }
    ++bcur; if (bcur == 3) bcur = 0;
  }
#undef STG2

  const int orow0 = rowBase + wm * 64 + g * 4;
  const int ocol0 = colBase + wn * 64 + lr;
  if constexpr (LORA) {
    float bl[4][8];
#pragma unroll
    for (int n = 0; n < 4; ++n) {
      const int cc = ocol0 + n * 16;
      const int fc = (cc < HID / 2) ? (2 * cc) : (2 * (cc - HID / 2) + 1);
#pragma unroll
      for (int e = 0; e < 8; ++e) bl[n][e] = BL[fc * LR + e];
    }
#pragma unroll
    for (int m = 0; m < 4; ++m) {
      float tr[4][8];
#pragma unroll
      for (int r2 = 0; r2 < 4; ++r2)
#pragma unroll
        for (int e = 0; e < 8; ++e) tr[r2][e] = T[(size_t)(orow0 + m * 16 + r2) * LR + e];
#pragma unroll
      for (int n = 0; n < 4; ++n)
#pragma unroll
        for (int r2 = 0; r2 < 4; ++r2) {
          float dot = 0.0f;
#pragma unroll
          for (int e = 0; e < 8; ++e) dot += tr[r2][e] * bl[n][e];
          outb[(size_t)(orow0 + m * 16 + r2) * HID + ocol0 + n * 16] =
              f2bf(acc[m][n][r2] + 2.0f * dot);
        }
    }
  } else {
#pragma unroll
    for (int m = 0; m < 4; ++m)
#pragma unroll
      for (int n = 0; n < 4; ++n)
#pragma unroll
        for (int r2 = 0; r2 < 4; ++r2)
          outf[(size_t)(orow0 + m * 16 + r2) * HID + ocol0 + n * 16] = acc[m][n][r2];
  }
}

// ---------------------------------------------------------------- causal flash attention v4
#define STAGE(buf_, kvb_)                                                                   \
  do {                                                                                      \
    _Pragma("unroll") for (int i_ = 0; i_ < 4; ++i_) {                                      \
      const int sb_ = (w * 4 + i_) * 64;                                                    \
      {                                                                                     \
        const int slot_ = sb_ + lane;                                                       \
        const int rr_ = slot_ >> 4, cc_ = slot_ & 15;                                       \
        __builtin_amdgcn_global_load_lds(                                                   \
            (glb_void*)(kg + (size_t)((kvb_) + rr_) * HID + h * HDIM +                      \
                        ((cc_ ^ (rr_ & 15)) << 3)),                                         \
            (lds_void*)(&Ks[buf_][sb_ * 8]), 16, 0, 0);                                     \
      }                                                                                     \
      {                                                                                     \
        const int slot_ = sb_ + lane;                                                       \
        const int rr_ = slot_ >> 3, cc_ = slot_ & 7;                                        \
        __builtin_amdgcn_global_load_lds(                                                   \
            (glb_void*)(vt + ((size_t)h * HDIM + rr_) * SEQ + (kvb_) +                      \
                        ((cc_ ^ (rr_ & 7)) << 3)),                                          \
            (lds_void*)(&Vs[buf_][sb_ * 8]), 16, 0, 0);                                     \
      }                                                                                     \
    }                                                                                       \
  } while (0)

__global__ __launch_bounds__(256, 2) void flash_attn4(const __hip_bfloat16* __restrict__ qg,
                                                      const __hip_bfloat16* __restrict__ kg,
                                                      const __hip_bfloat16* __restrict__ vt,
                                                      __hip_bfloat16* __restrict__ o) {
  __shared__ __hip_bfloat16 Ks[2][64 * 128];
  __shared__ __hip_bfloat16 Vs[2][128 * 64];
  const int tid = threadIdx.x;
  const int lane = tid & 63;
  const int w = tid >> 6;
  const int ql = lane & 31;
  const int hi = lane >> 5;
  const int bx = blockIdx.x;
  const int h = bx & 31;
  const int strip = (bx < 256) ? (bx >> 5) : (15 - ((bx - 256) >> 5));
  const float scale = 0.088388347648318447f;

  const int q0 = strip * 128 + w * 32;
  const int nt = 2 * strip + 2;
  const int qgl = q0 + ql;

  bf16x8 bq[8];
#pragma unroll
  for (int sl = 0; sl < 8; ++sl)
    bq[sl] = *reinterpret_cast<const bf16x8*>(qg + (size_t)qgl * HID + h * HDIM + sl * 16 + hi * 8);

  f32x16 accO[4];
#pragma unroll
  for (int db = 0; db < 4; ++db)
#pragma unroll
    for (int e = 0; e < 16; ++e) accO[db][e] = 0.0f;
  float m_run = -1e30f, lsum = 0.0f;

  int cur = 0;
  STAGE(0, 0);
  asm volatile("s_waitcnt vmcnt(0)");
  __syncthreads();

  for (int t = 0; t < nt; ++t) {
    const int kvb = t * 64;
    if (t + 1 < nt) STAGE(cur ^ 1, (t + 1) * 64);
    if (kvb <= q0 + 31) {
      f32x16 sc[2];
#pragma unroll
      for (int sub = 0; sub < 2; ++sub) {
#pragma unroll
        for (int e = 0; e < 16; ++e) sc[sub][e] = 0.0f;
        const int krow = sub * 32 + ql;
#pragma unroll
        for (int sl = 0; sl < 8; ++sl) {
          const int chh = (sl * 2 + hi) ^ (ql & 15);
          bf16x8 ak = *reinterpret_cast<const bf16x8*>(&Ks[cur][krow * 128 + chh * 8]);
          sc[sub] = __builtin_amdgcn_mfma_f32_32x32x16_bf16(ak, bq[sl], sc[sub], 0, 0, 0);
        }
      }
      float smax = -3.0e38f;
      if (kvb + 63 > q0) {
#pragma unroll
        for (int sub = 0; sub < 2; ++sub)
#pragma unroll
          for (int r = 0; r < 16; ++r) {
            const int kvg = kvb + sub * 32 + (r & 3) + 8 * (r >> 2) + 4 * hi;
            float v2 = sc[sub][r] * scale;
            v2 = (kvg > qgl) ? -3.0e38f : v2;
            sc[sub][r] = v2;
            smax = fmaxf(smax, v2);
          }
      } else {
#pragma unroll
        for (int sub = 0; sub < 2; ++sub)
#pragma unroll
          for (int r = 0; r < 16; ++r) {
            const float v2 = sc[sub][r] * scale;
            sc[sub][r] = v2;
            smax = fmaxf(smax, v2);
          }
      }
      smax = fmaxf(smax, __shfl_xor(smax, 32));
      if (__any(smax > m_run + 8.0f)) {
        const float mnew = fmaxf(m_run, smax);
        const float sca = __expf(m_run - mnew);
        m_run = mnew;
        lsum *= sca;
#pragma unroll
        for (int r = 0; r < 16; ++r) {
          const float sr = __shfl(sca, (r & 3) + 8 * (r >> 2) + 4 * hi);
#pragma unroll
          for (int db = 0; db < 4; ++db) accO[db][r] *= sr;
        }
      }
      float psum = 0.0f;
#pragma unroll
      for (int sub = 0; sub < 2; ++sub)
#pragma unroll
        for (int r = 0; r < 16; ++r) {
          const float p = __expf(sc[sub][r] - m_run);
          sc[sub][r] = p;
          psum += p;
        }
      psum += __shfl_xor(psum, 32);
      lsum += psum;
      bf16x8 pa[4];
#pragma unroll
      for (int sub = 0; sub < 2; ++sub) {
        const unsigned A0 = pkbf(sc[sub][0], sc[sub][1]);
        const unsigned C0 = pkbf(sc[sub][2], sc[sub][3]);
        const unsigned B0 = pkbf(sc[sub][4], sc[sub][5]);
        const unsigned D0 = pkbf(sc[sub][6], sc[sub][7]);
        const unsigned A1 = pkbf(sc[sub][8], sc[sub][9]);
        const unsigned C1 = pkbf(sc[sub][10], sc[sub][11]);
        const unsigned B1 = pkbf(sc[sub][12], sc[sub][13]);
        const unsigned D1 = pkbf(sc[sub][14], sc[sub][15]);
        const unsigned sA0 = (unsigned)__shfl_xor((int)A0, 32);
        const unsigned sB0 = (unsigned)__shfl_xor((int)B0, 32);
        const unsigned sC0 = (unsigned)__shfl_xor((int)C0, 32);
        const unsigned sD0 = (unsigned)__shfl_xor((int)D0, 32);
        const unsigned sA1 = (unsigned)__shfl_xor((int)A1, 32);
        const unsigned sB1 = (unsigned)__shfl_xor((int)B1, 32);
        const unsigned sC1 = (unsigned)__shfl_xor((int)C1, 32);
        const unsigned sD1 = (unsigned)__shfl_xor((int)D1, 32);
        union { unsigned u[4]; bf16x8 v; } f0, f1;
        f0.u[0] = hi ? sB0 : A0;
        f0.u[1] = hi ? sD0 : C0;
        f0.u[2] = hi ? B0 : sA0;
        f0.u[3] = hi ? D0 : sC0;
        f1.u[0] = hi ? sB1 : A1;
        f1.u[1] = hi ? sD1 : C1;
        f1.u[2] = hi ? B1 : sA1;
        f1.u[3] = hi ? D1 : sC1;
        pa[sub * 2 + 0] = f0.v;
        pa[sub * 2 + 1] = f1.v;
      }
#pragma unroll
      for (int db = 0; db < 4; ++db) {
        const int vrow = db * 32 + ql;
#pragma unroll
        for (int ks = 0; ks < 4; ++ks) {
          const int chh = (ks * 2 + hi) ^ (ql & 7);
          bf16x8 bv = *reinterpret_cast<const bf16x8*>(&Vs[cur][vrow * 64 + chh * 8]);
          accO[db] = __builtin_amdgcn_mfma_f32_32x32x16_bf16(pa[ks], bv, accO[db], 0, 0, 0);
        }
      }
    }
    asm volatile("s_waitcnt vmcnt(0)");
    __syncthreads();
    cur ^= 1;
  }
  const float il = 1.0f / lsum;
#pragma unroll
  for (int r = 0; r < 16; ++r) {
    const int rb = (r & 3) + 8 * (r >> 2);
    const float ir = __shfl(il, rb + 4 * hi);
    const int qrow = q0 + rb + 4 * hi;
#pragma unroll
    for (int db = 0; db < 4; ++db)
      o[(size_t)qrow * HID + h * HDIM + db * 32 + ql] = f2bf(accO[db][r] * ir);
  }
}

// ----------------------------------------------------------------
extern "C" void kernel_launch(void* const* d_in, const int* in_sizes, int n_in,
                              void* d_out, int out_size, void* d_ws, size_t ws_size,
                              hipStream_t stream) {
  (void)in_sizes; (void)n_in; (void)out_size; (void)ws_size;
  const float* x  = (const float*)d_in[0];
  const float* Wq = (const float*)d_in[1];
  const float* Wk = (const float*)d_in[2];
  const float* Wv = (const float*)d_in[3];
  const float* Wo = (const float*)d_in[4];
  const float* Aq = (const float*)d_in[5];
  const float* Bq = (const float*)d_in[6];
  const float* Ak = (const float*)d_in[7];
  const float* Bk = (const float*)d_in[8];
  const float* Av = (const float*)d_in[9];
  const float* Bv = (const float*)d_in[10];
  float* out = (float*)d_out;

  char* p = (char*)d_ws;
  __hip_bfloat16* xb   = (__hip_bfloat16*)p; p += (size_t)SEQ * HID * 2;       // reused as ab
  __hip_bfloat16* wqkv = (__hip_bfloat16*)p; p += (size_t)3 * HID * HID * 2;   // [0:32M] reused for Wo
  __hip_bfloat16* qb   = (__hip_bfloat16*)p; p += (size_t)SEQ * HID * 2;
  __hip_bfloat16* kb   = (__hip_bfloat16*)p; p += (size_t)SEQ * HID * 2;
  __hip_bfloat16* vb   = (__hip_bfloat16*)p; p += (size_t)SEQ * HID * 2;
  __hip_bfloat16* vtb  = (__hip_bfloat16*)p; p += (size_t)SEQ * HID * 2;
  float* tq   = (float*)p; p += SEQ * LR * 4;
  float* tk   = (float*)p; p += SEQ * LR * 4;
  float* tv   = (float*)p; p += SEQ * LR * 4;
  float* cosb = (float*)p; p += SEQ * 64 * 4;
  float* sinb = (float*)p; p += SEQ * 64 * 4;
  __hip_bfloat16* ab = xb;  // x no longer needed after QKV GEMMs

  conv_f32_bf16<<<SEQ * HID / 1024, 256, 0, stream>>>(x, xb, SEQ * HID / 4);
  lora_t<<<SEQ * 3 / 4, 256, 0, stream>>>(x, Aq, Ak, Av, tq, tk, tv);
  rope_tables<<<SEQ * 64 / 256, 256, 0, stream>>>(cosb, sinb);
  conv_f32_bf16<<<HID * HID / 1024, 256, 0, stream>>>(Wq, wqkv + 0 * (size_t)HID * HID, HID * HID / 4);
  conv_f32_bf16<<<HID * HID / 1024, 256, 0, stream>>>(Wk, wqkv + 1 * (size_t)HID * HID, HID * HID / 4);
  conv_f32_bf16<<<HID * HID / 1024, 256, 0, stream>>>(Wv, wqkv + 2 * (size_t)HID * HID, HID * HID / 4);

  gemm8<<<dim3(16, 8, 3), 512, 0, stream>>>(xb, wqkv, tq, tk, tv, Bq, Bk, Bv, qb, kb, vb);

  rope_apply<<<SEQ * NHEADS * 64 / 256, 256, 0, stream>>>(qb, cosb, sinb);
  rope_apply<<<SEQ * NHEADS * 64 / 256, 256, 0, stream>>>(kb, cosb, sinb);
  transpose_v<<<dim3(SEQ / 64, HDIM / 64, NHEADS), 256, 0, stream>>>(vb, vtb);
  flash_attn4<<<512, 256, 0, stream>>>(qb, kb, vtb, ab);

  conv_f32_bf16<<<HID * HID / 1024, 256, 0, stream>>>(Wo, wqkv, HID * HID / 4);
  gemm2<false><<<dim3(16, 16, 1), 512, 0, stream>>>(ab, wqkv, nullptr, nullptr, nullptr,
                                                    nullptr, nullptr, nullptr,
                                                    nullptr, nullptr, nullptr, out);
}

// Round 12
// 614.396 us; speedup vs baseline: 1.0329x; 1.0329x over previous
//
#include <hip/hip_runtime.h>
#include <hip/hip_bf16.h>

#define SEQ 2048
#define HID 4096
#define NHEADS 32
#define HDIM 128
#define LR 8

typedef __attribute__((ext_vector_type(8))) short bf16x8;
typedef __attribute__((ext_vector_type(4))) float f32x4;
typedef __attribute__((ext_vector_type(16))) float f32x16;

typedef __attribute__((address_space(3))) void lds_void;
typedef const __attribute__((address_space(1))) void glb_void;

static __device__ __forceinline__ float bf2f(__hip_bfloat16 v) { return __bfloat162float(v); }
static __device__ __forceinline__ __hip_bfloat16 f2bf(float v) { return __float2bfloat16(v); }

static __device__ __forceinline__ unsigned pkbf(float lo, float hi2) {
  __hip_bfloat16 l = __float2bfloat16(lo), h2 = __float2bfloat16(hi2);
  unsigned short ul = *reinterpret_cast<unsigned short*>(&l);
  unsigned short uh = *reinterpret_cast<unsigned short*>(&h2);
  return ((unsigned)uh << 16) | ul;
}

// ---------------------------------------------------------------- fp32 -> bf16
__global__ __launch_bounds__(256) void conv_f32_bf16(const float* __restrict__ src,
                                                     __hip_bfloat16* __restrict__ dst,
                                                     int n4) {
  const int i = blockIdx.x * 256 + threadIdx.x;
  if (i >= n4) return;
  const float4 v = reinterpret_cast<const float4*>(src)[i];
  union { __hip_bfloat16 h[4]; ushort4 u; } pk;
  pk.h[0] = f2bf(v.x); pk.h[1] = f2bf(v.y); pk.h[2] = f2bf(v.z); pk.h[3] = f2bf(v.w);
  reinterpret_cast<ushort4*>(dst)[i] = pk.u;
}

// ---------------------------------------------------------------- t = x @ A^T  (fp32, rank 8)
__global__ __launch_bounds__(256) void lora_t(const float* __restrict__ x,
                                              const float* __restrict__ Aq,
                                              const float* __restrict__ Ak,
                                              const float* __restrict__ Av,
                                              float* __restrict__ tq,
                                              float* __restrict__ tk,
                                              float* __restrict__ tv) {
  const int gw = blockIdx.x * 4 + (threadIdx.x >> 6);
  const int lane = threadIdx.x & 63;
  const int which = gw / SEQ;
  const int s = gw - which * SEQ;
  const float* A = (which == 0) ? Aq : (which == 1) ? Ak : Av;
  float* t = (which == 0) ? tq : (which == 1) ? tk : tv;
  float acc[LR];
#pragma unroll
  for (int r = 0; r < LR; ++r) acc[r] = 0.0f;
  const float4* xr = reinterpret_cast<const float4*>(x + (size_t)s * HID);
  for (int c = lane; c < HID / 4; c += 64) {
    const float4 xv = xr[c];
#pragma unroll
    for (int r = 0; r < LR; ++r) {
      const float4 av = reinterpret_cast<const float4*>(A + r * HID)[c];
      acc[r] += xv.x * av.x + xv.y * av.y + xv.z * av.z + xv.w * av.w;
    }
  }
#pragma unroll
  for (int r = 0; r < LR; ++r) {
    float vv = acc[r];
#pragma unroll
    for (int off = 32; off > 0; off >>= 1) vv += __shfl_down(vv, off);
    if (lane == 0) t[s * LR + r] = vv;
  }
}

// ---------------------------------------------------------------- RoPE cos/sin tables [S][64]
__global__ __launch_bounds__(256) void rope_tables(float* __restrict__ cosb,
                                                   float* __restrict__ sinb) {
  const int i = blockIdx.x * 256 + threadIdx.x;
  const int s = i >> 6, d = i & 63;
  const float invf = powf(10000.0f, -(float)d * (1.0f / 64.0f));
  const float ang = (float)s * invf;
  cosb[i] = cosf(ang);
  sinb[i] = sinf(ang);
}

// ---------------------------------------------------------------- RoPE in-place on bf16 (S,4096)
__global__ __launch_bounds__(256) void rope_apply(__hip_bfloat16* __restrict__ t,
                                                  const float* __restrict__ cosb,
                                                  const float* __restrict__ sinb) {
  const int i = blockIdx.x * 256 + threadIdx.x;
  const int d = i & 63;
  const int hh = (i >> 6) & (NHEADS - 1);
  const int s = i >> 11;
  const size_t base = (size_t)s * HID + hh * HDIM;
  const float x1 = bf2f(t[base + d]);
  const float x2 = bf2f(t[base + d + 64]);
  const float cc = cosb[s * 64 + d];
  const float ss = sinb[s * 64 + d];
  t[base + d] = f2bf(x1 * cc - x2 * ss);
  t[base + d + 64] = f2bf(x1 * ss + x2 * cc);
}

// ---------------------------------------------------------------- V (S,4096) -> Vt [h][d][s]
__global__ __launch_bounds__(256) void transpose_v(const __hip_bfloat16* __restrict__ v,
                                                   __hip_bfloat16* __restrict__ vt) {
  __shared__ __hip_bfloat16 tile[64][72];
  const int h = blockIdx.z;
  const int s0 = blockIdx.x * 64;
  const int db = blockIdx.y * 64;
  const int c = (threadIdx.x & 7) * 8;
  const int r = threadIdx.x >> 3;
#pragma unroll
  for (int p = 0; p < 2; ++p) {
    const int rr = r + p * 32;
    *reinterpret_cast<float4*>(&tile[rr][c]) =
        *reinterpret_cast<const float4*>(v + (size_t)(s0 + rr) * HID + h * HDIM + db + c);
  }
  __syncthreads();
#pragma unroll
  for (int p = 0; p < 2; ++p) {
    const int rr = r + p * 32;
    alignas(16) __hip_bfloat16 tmp[8];
#pragma unroll
    for (int j = 0; j < 8; ++j) tmp[j] = tile[c + j][rr];
    *reinterpret_cast<float4*>(vt + (size_t)(h * HDIM + db + rr) * SEQ + s0 + c) =
        *reinterpret_cast<float4*>(tmp);
  }
}

// ---------------------------------------------------------------- QKV GEMM v9: faithful m201-style 8-phase
// BM=BN=256, BK=64, 8 waves. Wave output = 128x64 but split per half: m-strip
// wm*64 in EACH A-half (rows h*128+wm*64..+63), n-strip wn*32 in EACH B-half.
// So quadrant (mh,nh) touches exactly A-half mh, B-half nh.
// LDS: Al/Bl[2dbuf][2half][128][64] = 128 KB. Phase (m201 order):
//   ds_read quadrant operands; stage ONE half-plane of tile j+1 (2 gload_lds);
//   s_barrier; lgkmcnt(0); setprio(1); 16 MFMA; setprio(0); [vmcnt(4)]; s_barrier.
// Stage stream per tile: [A0,B0,B1,A1] = consumption order. Per-wave FIFO
// (2 loads/stage): entering tile j ph1, outstanding = {B1(j),A1(j)} = 4.
//   end ph1 (staged A0'): out=6,  vmcnt(4) retires B1(j)  (read in ph2)
//   end ph2 (staged B0'): out=6,  vmcnt(4) retires A1(j)  (read in ph3)
//   end ph3 (staged B1'): out=6,  no wait
//   end ph4 (staged A1'): out=8,  vmcnt(4) retires A0',B0' (read in ph1 of j+1)
// Swizzle (both-sides): chunk c' = c ^ (row&7) over 8 16B-chunks/row; reads use
// (ks*4+g)^(lr&7) -> 2-way conflict (free). Reads/MFMA = 24/64 = 0.375.
__global__ __launch_bounds__(512, 2) void gemm9(const __hip_bfloat16* __restrict__ X,
                                                const __hip_bfloat16* __restrict__ wqkv,
                                                const float* __restrict__ tq,
                                                const float* __restrict__ tk,
                                                const float* __restrict__ tv,
                                                const float* __restrict__ Bq,
                                                const float* __restrict__ Bk,
                                                const float* __restrict__ Bv,
                                                __hip_bfloat16* __restrict__ qb,
                                                __hip_bfloat16* __restrict__ kb,
                                                __hip_bfloat16* __restrict__ vb) {
  __shared__ __hip_bfloat16 Al[2][2][128][64];  // 64 KB
  __shared__ __hip_bfloat16 Bl[2][2][128][64];  // 64 KB
  const int z = blockIdx.z;
  const __hip_bfloat16* W = wqkv + (size_t)z * HID * HID;
  const float* T = (z == 0) ? tq : (z == 1) ? tk : tv;
  const float* BL = (z == 0) ? Bq : (z == 1) ? Bk : Bv;
  __hip_bfloat16* outb = (z == 0) ? qb : (z == 1) ? kb : vb;

  const int tid = threadIdx.x;
  const int lane = tid & 63;
  const int w = tid >> 6;   // 0..7
  const int wm = w >> 2;    // 0..1: 64-row strip within each A-half
  const int wn = w & 3;     // 0..3: 32-col strip within each B-half
  const int g = lane >> 4, lr = lane & 15;

  // XCD col-panel swizzle: xcd = fid&7 owns col panels {2x,2x+1} (4MB W, L2-resident)
  const int fid = blockIdx.x + (blockIdx.y << 4);            // 0..127
  const int rowBase = (fid >> 4) * 256;
  const int colBase = ((fid & 7) * 2 + ((fid >> 3) & 1)) * 256;

  // staging: half-plane 128x64 = 1024 16B slots; slot s=(w*2+t)*64+lane
  const int s0 = (w * 2) * 64 + lane, s1 = s0 + 64;
  const int r0 = s0 >> 3, c0 = s0 & 7;
  const int r1 = s1 >> 3, c1 = s1 & 7;
  const __hip_bfloat16* Ags0 = X + (size_t)(rowBase + r0) * HID + ((c0 ^ (r0 & 7)) * 8);
  const __hip_bfloat16* Ags1 = X + (size_t)(rowBase + r1) * HID + ((c1 ^ (r1 & 7)) * 8);
  const __hip_bfloat16* Bgs0 = W + (size_t)(colBase + r0) * HID + ((c0 ^ (r0 & 7)) * 8);
  const __hip_bfloat16* Bgs1 = W + (size_t)(colBase + r1) * HID + ((c1 ^ (r1 & 7)) * 8);
  const size_t HOFF = (size_t)128 * HID;  // half1 offset (elements)

#define SGA9(buf_, h_, kk_)                                                         \
  do {                                                                              \
    __builtin_amdgcn_global_load_lds((glb_void*)(Ags0 + (h_) * HOFF + (kk_)),       \
        (lds_void*)(&Al[buf_][h_][0][0] + (w * 2) * 512), 16, 0, 0);                \
    __builtin_amdgcn_global_load_lds((glb_void*)(Ags1 + (h_) * HOFF + (kk_)),       \
        (lds_void*)(&Al[buf_][h_][0][0] + (w * 2 + 1) * 512), 16, 0, 0);            \
  } while (0)
#define SGB9(buf_, h_, kk_)                                                         \
  do {                                                                              \
    __builtin_amdgcn_global_load_lds((glb_void*)(Bgs0 + (h_) * HOFF + (kk_)),       \
        (lds_void*)(&Bl[buf_][h_][0][0] + (w * 2) * 512), 16, 0, 0);                \
    __builtin_amdgcn_global_load_lds((glb_void*)(Bgs1 + (h_) * HOFF + (kk_)),       \
        (lds_void*)(&Bl[buf_][h_][0][0] + (w * 2 + 1) * 512), 16, 0, 0);            \
  } while (0)

  f32x4 acc[2][2][4][2];  // [mh][nh][mf][nf]
#pragma unroll
  for (int a = 0; a < 2; ++a)
#pragma unroll
    for (int b = 0; b < 2; ++b)
#pragma unroll
      for (int m = 0; m < 4; ++m)
#pragma unroll
        for (int n = 0; n < 2; ++n)
#pragma unroll
          for (int e = 0; e < 4; ++e) acc[a][b][m][n][e] = 0.0f;

  // prologue: tile 0 halves in steady-state issue order [A0, B0, B1, A1]
  SGA9(0, 0, 0);
  __builtin_amdgcn_sched_barrier(0);
  SGB9(0, 0, 0);
  __builtin_amdgcn_sched_barrier(0);
  SGB9(0, 1, 0);
  __builtin_amdgcn_sched_barrier(0);
  SGA9(0, 1, 0);
  asm volatile("s_waitcnt vmcnt(4)" ::: "memory");  // retire A0,B0 of tile 0
  __syncthreads();

  bf16x8 af[4][2], b0[2][2], b1[2][2];
  for (int j = 0; j < 64; ++j) {
    const int cur = j & 1, nxt = cur ^ 1;
    const int kn = (j < 63 ? j + 1 : 63) * 64;  // tail: redundant re-stage keeps FIFO
    // ================ phase 1: quadrant (m0,n0); reads A-half0 + B-half0; stage A0'
#pragma unroll
    for (int mf = 0; mf < 4; ++mf)
#pragma unroll
      for (int ks = 0; ks < 2; ++ks)
        af[mf][ks] = *reinterpret_cast<const bf16x8*>(
            &Al[cur][0][wm * 64 + mf * 16 + lr][(((ks * 4 + g) ^ (lr & 7)) * 8)]);
#pragma unroll
    for (int nf = 0; nf < 2; ++nf)
#pragma unroll
      for (int ks = 0; ks < 2; ++ks)
        b0[nf][ks] = *reinterpret_cast<const bf16x8*>(
            &Bl[cur][0][wn * 32 + nf * 16 + lr][(((ks * 4 + g) ^ (lr & 7)) * 8)]);
    SGA9(nxt, 0, kn);
    __builtin_amdgcn_sched_barrier(0);
    __builtin_amdgcn_s_barrier();
    asm volatile("s_waitcnt lgkmcnt(0)" ::: "memory");
    __builtin_amdgcn_sched_barrier(0);
    __builtin_amdgcn_s_setprio(1);
#pragma unroll
    for (int mf = 0; mf < 4; ++mf)
#pragma unroll
      for (int nf = 0; nf < 2; ++nf)
#pragma unroll
        for (int ks = 0; ks < 2; ++ks)
          acc[0][0][mf][nf] =
              __builtin_amdgcn_mfma_f32_16x16x32_bf16(af[mf][ks], b0[nf][ks], acc[0][0][mf][nf], 0, 0, 0);
    __builtin_amdgcn_s_setprio(0);
    asm volatile("s_waitcnt vmcnt(4)" ::: "memory");  // retire B1(j) for ph2
    __builtin_amdgcn_sched_barrier(0);
    __builtin_amdgcn_s_barrier();
    // ================ phase 2: quadrant (m0,n1); reads B-half1; stage B0'
#pragma unroll
    for (int nf = 0; nf < 2; ++nf)
#pragma unroll
      for (int ks = 0; ks < 2; ++ks)
        b1[nf][ks] = *reinterpret_cast<const bf16x8*>(
            &Bl[cur][1][wn * 32 + nf * 16 + lr][(((ks * 4 + g) ^ (lr & 7)) * 8)]);
    SGB9(nxt, 0, kn);
    __builtin_amdgcn_sched_barrier(0);
    __builtin_amdgcn_s_barrier();
    asm volatile("s_waitcnt lgkmcnt(0)" ::: "memory");
    __builtin_amdgcn_sched_barrier(0);
    __builtin_amdgcn_s_setprio(1);
#pragma unroll
    for (int mf = 0; mf < 4; ++mf)
#pragma unroll
      for (int nf = 0; nf < 2; ++nf)
#pragma unroll
        for (int ks = 0; ks < 2; ++ks)
          acc[0][1][mf][nf] =
              __builtin_amdgcn_mfma_f32_16x16x32_bf16(af[mf][ks], b1[nf][ks], acc[0][1][mf][nf], 0, 0, 0);
    __builtin_amdgcn_s_setprio(0);
    asm volatile("s_waitcnt vmcnt(4)" ::: "memory");  // retire A1(j) for ph3
    __builtin_amdgcn_sched_barrier(0);
    __builtin_amdgcn_s_barrier();
    // ================ phase 3: quadrant (m1,n0); reads A-half1; stage B1'
#pragma unroll
    for (int mf = 0; mf < 4; ++mf)
#pragma unroll
      for (int ks = 0; ks < 2; ++ks)
        af[mf][ks] = *reinterpret_cast<const bf16x8*>(
            &Al[cur][1][wm * 64 + mf * 16 + lr][(((ks * 4 + g) ^ (lr & 7)) * 8)]);
    SGB9(nxt, 1, kn);
    __builtin_amdgcn_sched_barrier(0);
    __builtin_amdgcn_s_barrier();
    asm volatile("s_waitcnt lgkmcnt(0)" ::: "memory");
    __builtin_amdgcn_sched_barrier(0);
    __builtin_amdgcn_s_setprio(1);
#pragma unroll
    for (int mf = 0; mf < 4; ++mf)
#pragma unroll
      for (int nf = 0; nf < 2; ++nf)
#pragma unroll
        for (int ks = 0; ks < 2; ++ks)
          acc[1][0][mf][nf] =
              __builtin_amdgcn_mfma_f32_16x16x32_bf16(af[mf][ks], b0[nf][ks], acc[1][0][mf][nf], 0, 0, 0);
    __builtin_amdgcn_s_setprio(0);
    __builtin_amdgcn_s_barrier();  // no vmcnt here (ph4 reads nothing new)
    // ================ phase 4: quadrant (m1,n1); no reads; stage A1'
    SGA9(nxt, 1, kn);
    __builtin_amdgcn_sched_barrier(0);
    __builtin_amdgcn_s_barrier();
    __builtin_amdgcn_s_setprio(1);
#pragma unroll
    for (int mf = 0; mf < 4; ++mf)
#pragma unroll
      for (int nf = 0; nf < 2; ++nf)
#pragma unroll
        for (int ks = 0; ks < 2; ++ks)
          acc[1][1][mf][nf] =
              __builtin_amdgcn_mfma_f32_16x16x32_bf16(af[mf][ks], b1[nf][ks], acc[1][1][mf][nf], 0, 0, 0);
    __builtin_amdgcn_s_setprio(0);
    asm volatile("s_waitcnt vmcnt(4)" ::: "memory");  // retire A0',B0' for ph1 of j+1
    __builtin_amdgcn_sched_barrier(0);
    __builtin_amdgcn_s_barrier();
  }
#undef SGA9
#undef SGB9

  // epilogue: row = rowBase + mh*128 + wm*64 + mf*16 + g*4 + r2
  //           col = colBase + nh*128 + wn*32 + nf*16 + lr
#pragma unroll
  for (int mh = 0; mh < 2; ++mh)
#pragma unroll
    for (int mf = 0; mf < 4; ++mf) {
      const int orow0 = rowBase + mh * 128 + wm * 64 + mf * 16 + g * 4;
      float tr[4][8];
#pragma unroll
      for (int r2 = 0; r2 < 4; ++r2)
#pragma unroll
        for (int e = 0; e < 8; ++e) tr[r2][e] = T[(size_t)(orow0 + r2) * LR + e];
#pragma unroll
      for (int nh = 0; nh < 2; ++nh)
#pragma unroll
        for (int nf = 0; nf < 2; ++nf) {
          const int cc = colBase + nh * 128 + wn * 32 + nf * 16 + lr;
          const int fc = (cc < HID / 2) ? (2 * cc) : (2 * (cc - HID / 2) + 1);
          float bl[8];
#pragma unroll
          for (int e = 0; e < 8; ++e) bl[e] = BL[fc * LR + e];
#pragma unroll
          for (int r2 = 0; r2 < 4; ++r2) {
            float dot = 0.0f;
#pragma unroll
            for (int e = 0; e < 8; ++e) dot += tr[r2][e] * bl[e];
            outb[(size_t)(orow0 + r2) * HID + cc] = f2bf(acc[mh][nh][mf][nf][r2] + 2.0f * dot);
          }
        }
    }
}

// ---------------------------------------------------------------- Wo GEMM (proven counted-vmcnt, 3-buffer)
template <bool LORA>
__global__ __launch_bounds__(512, 2) void gemm2(const __hip_bfloat16* __restrict__ X,
                                                const __hip_bfloat16* __restrict__ wqkv,
                                                const float* __restrict__ tq,
                                                const float* __restrict__ tk,
                                                const float* __restrict__ tv,
                                                const float* __restrict__ Bq,
                                                const float* __restrict__ Bk,
                                                const float* __restrict__ Bv,
                                                __hip_bfloat16* __restrict__ qb,
                                                __hip_bfloat16* __restrict__ kb,
                                                __hip_bfloat16* __restrict__ vb,
                                                float* __restrict__ outf) {
  __shared__ __hip_bfloat16 Al[3][2][128][32];
  __shared__ __hip_bfloat16 Bl[3][2][256][32];
  const int z = blockIdx.z;
  const __hip_bfloat16* W = wqkv + (size_t)z * HID * HID;
  const float* T = (z == 0) ? tq : (z == 1) ? tk : tv;
  const float* BL = (z == 0) ? Bq : (z == 1) ? Bk : Bv;
  __hip_bfloat16* outb = (z == 0) ? qb : (z == 1) ? kb : vb;

  const int tid = threadIdx.x;
  const int lane = tid & 63;
  const int w = tid >> 6;
  const int wm = w >> 2;
  const int wn = w & 3;
  const int g = lane >> 4, lr = lane & 15;

  const int fid = blockIdx.x + (blockIdx.y << 4);
  const int xcd = fid & 7;
  const int j8 = fid >> 3;
  const int rowBase = (j8 >> 1) * 128;
  const int colBase = (xcd * 2 + (j8 & 1)) * 256;

  const int sA = w * 64 + lane;
  const int rA = sA >> 2, cA = sA & 3;
  const __hip_bfloat16* Ag = X + (size_t)(rowBase + rA) * HID + ((cA ^ ((rA >> 1) & 3)) * 8);
  const int sB0 = (w * 2) * 64 + lane;
  const int sB1 = (w * 2 + 1) * 64 + lane;
  const int rB0 = sB0 >> 2, cB0 = sB0 & 3;
  const int rB1 = sB1 >> 2, cB1 = sB1 & 3;
  const __hip_bfloat16* Bg0 = W + (size_t)(colBase + rB0) * HID + ((cB0 ^ ((rB0 >> 1) & 3)) * 8);
  const __hip_bfloat16* Bg1 = W + (size_t)(colBase + rB1) * HID + ((cB1 ^ ((rB1 >> 1) & 3)) * 8);

#define STG2(buf_, kh_, kk_)                                                        \
  do {                                                                              \
    __builtin_amdgcn_global_load_lds((glb_void*)(Ag + (kk_) + (kh_) * 32),          \
        (lds_void*)(&Al[buf_][kh_][0][0] + w * 512), 16, 0, 0);                     \
    __builtin_amdgcn_global_load_lds((glb_void*)(Bg0 + (kk_) + (kh_) * 32),         \
        (lds_void*)(&Bl[buf_][kh_][0][0] + (w * 2) * 512), 16, 0, 0);               \
    __builtin_amdgcn_global_load_lds((glb_void*)(Bg1 + (kk_) + (kh_) * 32),         \
        (lds_void*)(&Bl[buf_][kh_][0][0] + (w * 2 + 1) * 512), 16, 0, 0);           \
  } while (0)

  f32x4 acc[4][4];
#pragma unroll
  for (int m = 0; m < 4; ++m)
#pragma unroll
    for (int n = 0; n < 4; ++n)
#pragma unroll
      for (int e = 0; e < 4; ++e) acc[m][n][e] = 0.0f;

  const int ch = (g ^ ((lr >> 1) & 3)) * 8;

  STG2(0, 0, 0);
  __builtin_amdgcn_sched_barrier(0);
  STG2(0, 1, 0);
  __builtin_amdgcn_sched_barrier(0);
  STG2(1, 0, 64);
  __builtin_amdgcn_sched_barrier(0);
  STG2(1, 1, 64);

  int bcur = 0;
  for (int j = 0; j < 64; ++j) {
    int bn2 = bcur + 2; if (bn2 >= 3) bn2 -= 3;
    const int kn = (j < 62 ? j + 2 : 63) * 64;
#pragma unroll
    for (int kh = 0; kh < 2; ++kh) {
      asm volatile("s_waitcnt vmcnt(9) lgkmcnt(0)" ::: "memory");
      __builtin_amdgcn_s_barrier();
      __builtin_amdgcn_sched_barrier(0);
      bf16x8 af[4], bfr[4];
#pragma unroll
      for (int m = 0; m < 4; ++m)
        af[m] = *reinterpret_cast<const bf16x8*>(&Al[bcur][kh][wm * 64 + m * 16 + lr][ch]);
#pragma unroll
      for (int n = 0; n < 4; ++n)
        bfr[n] = *reinterpret_cast<const bf16x8*>(&Bl[bcur][kh][wn * 64 + n * 16 + lr][ch]);
      if (kh == 0) STG2(bn2, 0, kn); else STG2(bn2, 1, kn);
      __builtin_amdgcn_sched_barrier(0);
      __builtin_amdgcn_s_setprio(1);
#pragma unroll
      for (int m = 0; m < 4; ++m)
#pragma unroll
        for (int n = 0; n < 4; ++n)
          acc[m][n] = __builtin_amdgcn_mfma_f32_16x16x32_bf16(af[m], bfr[n], acc[m][n], 0, 0, 0);
      __builtin_amdgcn_s_setprio(0);
    }
    ++bcur; if (bcur == 3) bcur = 0;
  }
#undef STG2

  const int orow0 = rowBase + wm * 64 + g * 4;
  const int ocol0 = colBase + wn * 64 + lr;
  if constexpr (LORA) {
    float bl[4][8];
#pragma unroll
    for (int n = 0; n < 4; ++n) {
      const int cc = ocol0 + n * 16;
      const int fc = (cc < HID / 2) ? (2 * cc) : (2 * (cc - HID / 2) + 1);
#pragma unroll
      for (int e = 0; e < 8; ++e) bl[n][e] = BL[fc * LR + e];
    }
#pragma unroll
    for (int m = 0; m < 4; ++m) {
      float tr[4][8];
#pragma unroll
      for (int r2 = 0; r2 < 4; ++r2)
#pragma unroll
        for (int e = 0; e < 8; ++e) tr[r2][e] = T[(size_t)(orow0 + m * 16 + r2) * LR + e];
#pragma unroll
      for (int n = 0; n < 4; ++n)
#pragma unroll
        for (int r2 = 0; r2 < 4; ++r2) {
          float dot = 0.0f;
#pragma unroll
          for (int e = 0; e < 8; ++e) dot += tr[r2][e] * bl[n][e];
          outb[(size_t)(orow0 + m * 16 + r2) * HID + ocol0 + n * 16] =
              f2bf(acc[m][n][r2] + 2.0f * dot);
        }
    }
  } else {
#pragma unroll
    for (int m = 0; m < 4; ++m)
#pragma unroll
      for (int n = 0; n < 4; ++n)
#pragma unroll
        for (int r2 = 0; r2 < 4; ++r2)
          outf[(size_t)(orow0 + m * 16 + r2) * HID + ocol0 + n * 16] = acc[m][n][r2];
  }
}

// ---------------------------------------------------------------- causal flash attention v4
#define STAGE(buf_, kvb_)                                                                   \
  do {                                                                                      \
    _Pragma("unroll") for (int i_ = 0; i_ < 4; ++i_) {                                      \
      const int sb_ = (w * 4 + i_) * 64;                                                    \
      {                                                                                     \
        const int slot_ = sb_ + lane;                                                       \
        const int rr_ = slot_ >> 4, cc_ = slot_ & 15;                                       \
        __builtin_amdgcn_global_load_lds(                                                   \
            (glb_void*)(kg + (size_t)((kvb_) + rr_) * HID + h * HDIM +                      \
                        ((cc_ ^ (rr_ & 15)) << 3)),                                         \
            (lds_void*)(&Ks[buf_][sb_ * 8]), 16, 0, 0);                                     \
      }                                                                                     \
      {                                                                                     \
        const int slot_ = sb_ + lane;                                                       \
        const int rr_ = slot_ >> 3, cc_ = slot_ & 7;                                        \
        __builtin_amdgcn_global_load_lds(                                                   \
            (glb_void*)(vt + ((size_t)h * HDIM + rr_) * SEQ + (kvb_) +                      \
                        ((cc_ ^ (rr_ & 7)) << 3)),                                          \
            (lds_void*)(&Vs[buf_][sb_ * 8]), 16, 0, 0);                                     \
      }                                                                                     \
    }                                                                                       \
  } while (0)

__global__ __launch_bounds__(256, 2) void flash_attn4(const __hip_bfloat16* __restrict__ qg,
                                                      const __hip_bfloat16* __restrict__ kg,
                                                      const __hip_bfloat16* __restrict__ vt,
                                                      __hip_bfloat16* __restrict__ o) {
  __shared__ __hip_bfloat16 Ks[2][64 * 128];
  __shared__ __hip_bfloat16 Vs[2][128 * 64];
  const int tid = threadIdx.x;
  const int lane = tid & 63;
  const int w = tid >> 6;
  const int ql = lane & 31;
  const int hi = lane >> 5;
  const int bx = blockIdx.x;
  const int h = bx & 31;
  const int strip = (bx < 256) ? (bx >> 5) : (15 - ((bx - 256) >> 5));
  const float scale = 0.088388347648318447f;

  const int q0 = strip * 128 + w * 32;
  const int nt = 2 * strip + 2;
  const int qgl = q0 + ql;

  bf16x8 bq[8];
#pragma unroll
  for (int sl = 0; sl < 8; ++sl)
    bq[sl] = *reinterpret_cast<const bf16x8*>(qg + (size_t)qgl * HID + h * HDIM + sl * 16 + hi * 8);

  f32x16 accO[4];
#pragma unroll
  for (int db = 0; db < 4; ++db)
#pragma unroll
    for (int e = 0; e < 16; ++e) accO[db][e] = 0.0f;
  float m_run = -1e30f, lsum = 0.0f;

  int cur = 0;
  STAGE(0, 0);
  asm volatile("s_waitcnt vmcnt(0)");
  __syncthreads();

  for (int t = 0; t < nt; ++t) {
    const int kvb = t * 64;
    if (t + 1 < nt) STAGE(cur ^ 1, (t + 1) * 64);
    if (kvb <= q0 + 31) {
      f32x16 sc[2];
#pragma unroll
      for (int sub = 0; sub < 2; ++sub) {
#pragma unroll
        for (int e = 0; e < 16; ++e) sc[sub][e] = 0.0f;
        const int krow = sub * 32 + ql;
#pragma unroll
        for (int sl = 0; sl < 8; ++sl) {
          const int chh = (sl * 2 + hi) ^ (ql & 15);
          bf16x8 ak = *reinterpret_cast<const bf16x8*>(&Ks[cur][krow * 128 + chh * 8]);
          sc[sub] = __builtin_amdgcn_mfma_f32_32x32x16_bf16(ak, bq[sl], sc[sub], 0, 0, 0);
        }
      }
      float smax = -3.0e38f;
      if (kvb + 63 > q0) {
#pragma unroll
        for (int sub = 0; sub < 2; ++sub)
#pragma unroll
          for (int r = 0; r < 16; ++r) {
            const int kvg = kvb + sub * 32 + (r & 3) + 8 * (r >> 2) + 4 * hi;
            float v2 = sc[sub][r] * scale;
            v2 = (kvg > qgl) ? -3.0e38f : v2;
            sc[sub][r] = v2;
            smax = fmaxf(smax, v2);
          }
      } else {
#pragma unroll
        for (int sub = 0; sub < 2; ++sub)
#pragma unroll
          for (int r = 0; r < 16; ++r) {
            const float v2 = sc[sub][r] * scale;
            sc[sub][r] = v2;
            smax = fmaxf(smax, v2);
          }
      }
      smax = fmaxf(smax, __shfl_xor(smax, 32));
      if (__any(smax > m_run + 8.0f)) {
        const float mnew = fmaxf(m_run, smax);
        const float sca = __expf(m_run - mnew);
        m_run = mnew;
        lsum *= sca;
#pragma unroll
        for (int r = 0; r < 16; ++r) {
          const float sr = __shfl(sca, (r & 3) + 8 * (r >> 2) + 4 * hi);
#pragma unroll
          for (int db = 0; db < 4; ++db) accO[db][r] *= sr;
        }
      }
      float psum = 0.0f;
#pragma unroll
      for (int sub = 0; sub < 2; ++sub)
#pragma unroll
        for (int r = 0; r < 16; ++r) {
          const float p = __expf(sc[sub][r] - m_run);
          sc[sub][r] = p;
          psum += p;
        }
      psum += __shfl_xor(psum, 32);
      lsum += psum;
      bf16x8 pa[4];
#pragma unroll
      for (int sub = 0; sub < 2; ++sub) {
        const unsigned A0 = pkbf(sc[sub][0], sc[sub][1]);
        const unsigned C0 = pkbf(sc[sub][2], sc[sub][3]);
        const unsigned B0 = pkbf(sc[sub][4], sc[sub][5]);
        const unsigned D0 = pkbf(sc[sub][6], sc[sub][7]);
        const unsigned A1 = pkbf(sc[sub][8], sc[sub][9]);
        const unsigned C1 = pkbf(sc[sub][10], sc[sub][11]);
        const unsigned B1 = pkbf(sc[sub][12], sc[sub][13]);
        const unsigned D1 = pkbf(sc[sub][14], sc[sub][15]);
        const unsigned sA0 = (unsigned)__shfl_xor((int)A0, 32);
        const unsigned sB0 = (unsigned)__shfl_xor((int)B0, 32);
        const unsigned sC0 = (unsigned)__shfl_xor((int)C0, 32);
        const unsigned sD0 = (unsigned)__shfl_xor((int)D0, 32);
        const unsigned sA1 = (unsigned)__shfl_xor((int)A1, 32);
        const unsigned sB1 = (unsigned)__shfl_xor((int)B1, 32);
        const unsigned sC1 = (unsigned)__shfl_xor((int)C1, 32);
        const unsigned sD1 = (unsigned)__shfl_xor((int)D1, 32);
        union { unsigned u[4]; bf16x8 v; } f0, f1;
        f0.u[0] = hi ? sB0 : A0;
        f0.u[1] = hi ? sD0 : C0;
        f0.u[2] = hi ? B0 : sA0;
        f0.u[3] = hi ? D0 : sC0;
        f1.u[0] = hi ? sB1 : A1;
        f1.u[1] = hi ? sD1 : C1;
        f1.u[2] = hi ? B1 : sA1;
        f1.u[3] = hi ? D1 : sC1;
        pa[sub * 2 + 0] = f0.v;
        pa[sub * 2 + 1] = f1.v;
      }
#pragma unroll
      for (int db = 0; db < 4; ++db) {
        const int vrow = db * 32 + ql;
#pragma unroll
        for (int ks = 0; ks < 4; ++ks) {
          const int chh = (ks * 2 + hi) ^ (ql & 7);
          bf16x8 bv = *reinterpret_cast<const bf16x8*>(&Vs[cur][vrow * 64 + chh * 8]);
          accO[db] = __builtin_amdgcn_mfma_f32_32x32x16_bf16(pa[ks], bv, accO[db], 0, 0, 0);
        }
      }
    }
    asm volatile("s_waitcnt vmcnt(0)");
    __syncthreads();
    cur ^= 1;
  }
  const float il = 1.0f / lsum;
#pragma unroll
  for (int r = 0; r < 16; ++r) {
    const int rb = (r & 3) + 8 * (r >> 2);
    const float ir = __shfl(il, rb + 4 * hi);
    const int qrow = q0 + rb + 4 * hi;
#pragma unroll
    for (int db = 0; db < 4; ++db)
      o[(size_t)qrow * HID + h * HDIM + db * 32 + ql] = f2bf(accO[db][r] * ir);
  }
}

// ----------------------------------------------------------------
extern "C" void kernel_launch(void* const* d_in, const int* in_sizes, int n_in,
                              void* d_out, int out_size, void* d_ws, size_t ws_size,
                              hipStream_t stream) {
  (void)in_sizes; (void)n_in; (void)out_size; (void)ws_size;
  const float* x  = (const float*)d_in[0];
  const float* Wq = (const float*)d_in[1];
  const float* Wk = (const float*)d_in[2];
  const float* Wv = (const float*)d_in[3];
  const float* Wo = (const float*)d_in[4];
  const float* Aq = (const float*)d_in[5];
  const float* Bq = (const float*)d_in[6];
  const float* Ak = (const float*)d_in[7];
  const float* Bk = (const float*)d_in[8];
  const float* Av = (const float*)d_in[9];
  const float* Bv = (const float*)d_in[10];
  float* out = (float*)d_out;

  char* p = (char*)d_ws;
  __hip_bfloat16* xb   = (__hip_bfloat16*)p; p += (size_t)SEQ * HID * 2;       // reused as ab
  __hip_bfloat16* wqkv = (__hip_bfloat16*)p; p += (size_t)3 * HID * HID * 2;   // [0:32M] reused for Wo
  __hip_bfloat16* qb   = (__hip_bfloat16*)p; p += (size_t)SEQ * HID * 2;
  __hip_bfloat16* kb   = (__hip_bfloat16*)p; p += (size_t)SEQ * HID * 2;
  __hip_bfloat16* vb   = (__hip_bfloat16*)p; p += (size_t)SEQ * HID * 2;
  __hip_bfloat16* vtb  = (__hip_bfloat16*)p; p += (size_t)SEQ * HID * 2;
  float* tq   = (float*)p; p += SEQ * LR * 4;
  float* tk   = (float*)p; p += SEQ * LR * 4;
  float* tv   = (float*)p; p += SEQ * LR * 4;
  float* cosb = (float*)p; p += SEQ * 64 * 4;
  float* sinb = (float*)p; p += SEQ * 64 * 4;
  __hip_bfloat16* ab = xb;  // x no longer needed after QKV GEMMs

  conv_f32_bf16<<<SEQ * HID / 1024, 256, 0, stream>>>(x, xb, SEQ * HID / 4);
  lora_t<<<SEQ * 3 / 4, 256, 0, stream>>>(x, Aq, Ak, Av, tq, tk, tv);
  rope_tables<<<SEQ * 64 / 256, 256, 0, stream>>>(cosb, sinb);
  conv_f32_bf16<<<HID * HID / 1024, 256, 0, stream>>>(Wq, wqkv + 0 * (size_t)HID * HID, HID * HID / 4);
  conv_f32_bf16<<<HID * HID / 1024, 256, 0, stream>>>(Wk, wqkv + 1 * (size_t)HID * HID, HID * HID / 4);
  conv_f32_bf16<<<HID * HID / 1024, 256, 0, stream>>>(Wv, wqkv + 2 * (size_t)HID * HID, HID * HID / 4);

  gemm9<<<dim3(16, 8, 3), 512, 0, stream>>>(xb, wqkv, tq, tk, tv, Bq, Bk, Bv, qb, kb, vb);

  rope_apply<<<SEQ * NHEADS * 64 / 256, 256, 0, stream>>>(qb, cosb, sinb);
  rope_apply<<<SEQ * NHEADS * 64 / 256, 256, 0, stream>>>(kb, cosb, sinb);
  transpose_v<<<dim3(SEQ / 64, HDIM / 64, NHEADS), 256, 0, stream>>>(vb, vtb);
  flash_attn4<<<512, 256, 0, stream>>>(qb, kb, vtb, ab);

  conv_f32_bf16<<<HID * HID / 1024, 256, 0, stream>>>(Wo, wqkv, HID * HID / 4);
  gemm2<false><<<dim3(16, 16, 1), 512, 0, stream>>>(ab, wqkv, nullptr, nullptr, nullptr,
                                                    nullptr, nullptr, nullptr,
                                                    nullptr, nullptr, nullptr, out);
}

// Round 13
// 518.246 us; speedup vs baseline: 1.2246x; 1.1855x over previous
//
#include <hip/hip_runtime.h>
#include <hip/hip_bf16.h>

#define SEQ 2048
#define HID 4096
#define NHEADS 32
#define HDIM 128
#define LR 8

typedef __attribute__((ext_vector_type(8))) short bf16x8;
typedef __attribute__((ext_vector_type(4))) float f32x4;
typedef __attribute__((ext_vector_type(16))) float f32x16;

typedef __attribute__((address_space(3))) void lds_void;
typedef const __attribute__((address_space(1))) void glb_void;

static __device__ __forceinline__ float bf2f(__hip_bfloat16 v) { return __bfloat162float(v); }
static __device__ __forceinline__ __hip_bfloat16 f2bf(float v) { return __float2bfloat16(v); }

static __device__ __forceinline__ unsigned pkbf(float lo, float hi2) {
  __hip_bfloat16 l = __float2bfloat16(lo), h2 = __float2bfloat16(hi2);
  unsigned short ul = *reinterpret_cast<unsigned short*>(&l);
  unsigned short uh = *reinterpret_cast<unsigned short*>(&h2);
  return ((unsigned)uh << 16) | ul;
}

// ---------------------------------------------------------------- fp32 -> bf16
__global__ __launch_bounds__(256) void conv_f32_bf16(const float* __restrict__ src,
                                                     __hip_bfloat16* __restrict__ dst,
                                                     int n4) {
  const int i = blockIdx.x * 256 + threadIdx.x;
  if (i >= n4) return;
  const float4 v = reinterpret_cast<const float4*>(src)[i];
  union { __hip_bfloat16 h[4]; ushort4 u; } pk;
  pk.h[0] = f2bf(v.x); pk.h[1] = f2bf(v.y); pk.h[2] = f2bf(v.z); pk.h[3] = f2bf(v.w);
  reinterpret_cast<ushort4*>(dst)[i] = pk.u;
}

// ---------------------------------------------------------------- t = x @ A^T  (fp32, rank 8)
__global__ __launch_bounds__(256) void lora_t(const float* __restrict__ x,
                                              const float* __restrict__ Aq,
                                              const float* __restrict__ Ak,
                                              const float* __restrict__ Av,
                                              float* __restrict__ tq,
                                              float* __restrict__ tk,
                                              float* __restrict__ tv) {
  const int gw = blockIdx.x * 4 + (threadIdx.x >> 6);
  const int lane = threadIdx.x & 63;
  const int which = gw / SEQ;
  const int s = gw - which * SEQ;
  const float* A = (which == 0) ? Aq : (which == 1) ? Ak : Av;
  float* t = (which == 0) ? tq : (which == 1) ? tk : tv;
  float acc[LR];
#pragma unroll
  for (int r = 0; r < LR; ++r) acc[r] = 0.0f;
  const float4* xr = reinterpret_cast<const float4*>(x + (size_t)s * HID);
  for (int c = lane; c < HID / 4; c += 64) {
    const float4 xv = xr[c];
#pragma unroll
    for (int r = 0; r < LR; ++r) {
      const float4 av = reinterpret_cast<const float4*>(A + r * HID)[c];
      acc[r] += xv.x * av.x + xv.y * av.y + xv.z * av.z + xv.w * av.w;
    }
  }
#pragma unroll
  for (int r = 0; r < LR; ++r) {
    float vv = acc[r];
#pragma unroll
    for (int off = 32; off > 0; off >>= 1) vv += __shfl_down(vv, off);
    if (lane == 0) t[s * LR + r] = vv;
  }
}

// ---------------------------------------------------------------- RoPE cos/sin tables [S][64]
__global__ __launch_bounds__(256) void rope_tables(float* __restrict__ cosb,
                                                   float* __restrict__ sinb) {
  const int i = blockIdx.x * 256 + threadIdx.x;
  const int s = i >> 6, d = i & 63;
  const float invf = powf(10000.0f, -(float)d * (1.0f / 64.0f));
  const float ang = (float)s * invf;
  cosb[i] = cosf(ang);
  sinb[i] = sinf(ang);
}

// ---------------------------------------------------------------- RoPE in-place on bf16 (S,4096)
__global__ __launch_bounds__(256) void rope_apply(__hip_bfloat16* __restrict__ t,
                                                  const float* __restrict__ cosb,
                                                  const float* __restrict__ sinb) {
  const int i = blockIdx.x * 256 + threadIdx.x;
  const int d = i & 63;
  const int hh = (i >> 6) & (NHEADS - 1);
  const int s = i >> 11;
  const size_t base = (size_t)s * HID + hh * HDIM;
  const float x1 = bf2f(t[base + d]);
  const float x2 = bf2f(t[base + d + 64]);
  const float cc = cosb[s * 64 + d];
  const float ss = sinb[s * 64 + d];
  t[base + d] = f2bf(x1 * cc - x2 * ss);
  t[base + d + 64] = f2bf(x1 * ss + x2 * cc);
}

// ---------------------------------------------------------------- V (S,4096) -> Vt [h][d][s]
__global__ __launch_bounds__(256) void transpose_v(const __hip_bfloat16* __restrict__ v,
                                                   __hip_bfloat16* __restrict__ vt) {
  __shared__ __hip_bfloat16 tile[64][72];
  const int h = blockIdx.z;
  const int s0 = blockIdx.x * 64;
  const int db = blockIdx.y * 64;
  const int c = (threadIdx.x & 7) * 8;
  const int r = threadIdx.x >> 3;
#pragma unroll
  for (int p = 0; p < 2; ++p) {
    const int rr = r + p * 32;
    *reinterpret_cast<float4*>(&tile[rr][c]) =
        *reinterpret_cast<const float4*>(v + (size_t)(s0 + rr) * HID + h * HDIM + db + c);
  }
  __syncthreads();
#pragma unroll
  for (int p = 0; p < 2; ++p) {
    const int rr = r + p * 32;
    alignas(16) __hip_bfloat16 tmp[8];
#pragma unroll
    for (int j = 0; j < 8; ++j) tmp[j] = tile[c + j][rr];
    *reinterpret_cast<float4*>(vt + (size_t)(h * HDIM + db + rr) * SEQ + s0 + c) =
        *reinterpret_cast<float4*>(tmp);
  }
}

// ---------------------------------------------------------------- counted-vmcnt GEMM, BM=BN=128 BK=64
// R13: the proven R7 inner body (counted-vmcnt, T2 both-sides swizzle, setprio) at
// 256 threads / 4 waves, LDS 64 KB -> 2 blocks/CU = 2 INDEPENDENT barrier domains
// (m114: one block's MFMA covers the other's barrier drain). 4 gload_lds per
// thread per kh-phase; prologue 8 outstanding; vmcnt(4) at phase top retires
// exactly the kh-plane being read. XCD x owns 4 col-tiles = 4MB W (L2-resident).
template <bool LORA>
__global__ __launch_bounds__(256, 2) void gemm128(const __hip_bfloat16* __restrict__ X,
                                                  const __hip_bfloat16* __restrict__ wqkv,
                                                  const float* __restrict__ tq,
                                                  const float* __restrict__ tk,
                                                  const float* __restrict__ tv,
                                                  const float* __restrict__ Bq,
                                                  const float* __restrict__ Bk,
                                                  const float* __restrict__ Bv,
                                                  __hip_bfloat16* __restrict__ qb,
                                                  __hip_bfloat16* __restrict__ kb,
                                                  __hip_bfloat16* __restrict__ vb,
                                                  float* __restrict__ outf) {
  __shared__ __hip_bfloat16 Al[2][2][128][32];  // 32 KB
  __shared__ __hip_bfloat16 Bl[2][2][128][32];  // 32 KB
  const int z = blockIdx.z;
  const __hip_bfloat16* W = wqkv + (size_t)z * HID * HID;
  const float* T = (z == 0) ? tq : (z == 1) ? tk : tv;
  const float* BL = (z == 0) ? Bq : (z == 1) ? Bk : Bv;
  __hip_bfloat16* outb = (z == 0) ? qb : (z == 1) ? kb : vb;

  const int tid = threadIdx.x;
  const int lane = tid & 63;
  const int w = tid >> 6;   // 0..3
  const int wm = w >> 1;    // 0..1
  const int wn = w & 1;     // 0..1
  const int g = lane >> 4, lr = lane & 15;

  // XCD col-tile swizzle: xcd = fid&7 owns col-tiles {4x..4x+3} = 512 cols = 4MB W
  const int fid = blockIdx.x + (blockIdx.y << 5);  // bx 0..31, by 0..15 -> 0..511
  const int xcd = fid & 7;
  const int j8 = fid >> 3;                         // 0..63
  const int rowBase = (j8 >> 2) * 128;             // 0..15
  const int colBase = (xcd * 4 + (j8 & 3)) * 128;  // 0..31

  // staging: per (operand,kh) plane 128x32 bf16 = 512 16B slots; 2 slots/thread
  const int s0 = tid;           // slot 0
  const int s1 = tid + 256;     // slot 1
  const int r0 = s0 >> 2, c0 = s0 & 3;
  const int r1 = s1 >> 2, c1 = s1 & 3;
  const __hip_bfloat16* Ag0 = X + (size_t)(rowBase + r0) * HID + ((c0 ^ ((r0 >> 1) & 3)) * 8);
  const __hip_bfloat16* Ag1 = X + (size_t)(rowBase + r1) * HID + ((c1 ^ ((r1 >> 1) & 3)) * 8);
  const __hip_bfloat16* Bg0 = W + (size_t)(colBase + r0) * HID + ((c0 ^ ((r0 >> 1) & 3)) * 8);
  const __hip_bfloat16* Bg1 = W + (size_t)(colBase + r1) * HID + ((c1 ^ ((r1 >> 1) & 3)) * 8);

#define STG128(buf_, kh_, kk_)                                                      \
  do {                                                                              \
    __builtin_amdgcn_global_load_lds((glb_void*)(Ag0 + (kk_) + (kh_) * 32),         \
        (lds_void*)(&Al[buf_][kh_][0][0] + w * 512), 16, 0, 0);                     \
    __builtin_amdgcn_global_load_lds((glb_void*)(Ag1 + (kk_) + (kh_) * 32),         \
        (lds_void*)(&Al[buf_][kh_][0][0] + w * 512 + 2048), 16, 0, 0);              \
    __builtin_amdgcn_global_load_lds((glb_void*)(Bg0 + (kk_) + (kh_) * 32),         \
        (lds_void*)(&Bl[buf_][kh_][0][0] + w * 512), 16, 0, 0);                     \
    __builtin_amdgcn_global_load_lds((glb_void*)(Bg1 + (kk_) + (kh_) * 32),         \
        (lds_void*)(&Bl[buf_][kh_][0][0] + w * 512 + 2048), 16, 0, 0);              \
  } while (0)

  f32x4 acc[4][4];
#pragma unroll
  for (int m = 0; m < 4; ++m)
#pragma unroll
    for (int n = 0; n < 4; ++n)
#pragma unroll
      for (int e = 0; e < 4; ++e) acc[m][n][e] = 0.0f;

  const int ch = (g ^ ((lr >> 1) & 3)) * 8;  // swizzled read chunk

  STG128(0, 0, 0);
  __builtin_amdgcn_sched_barrier(0);
  STG128(0, 1, 0);

  for (int j = 0; j < 64; ++j) {
    const int cur = j & 1, nxt = cur ^ 1;
    const int kn = (j < 63 ? j + 1 : 63) * 64;  // tail: redundant re-stage keeps FIFO
#pragma unroll
    for (int kh = 0; kh < 2; ++kh) {
      asm volatile("s_waitcnt vmcnt(4) lgkmcnt(0)" ::: "memory");
      __builtin_amdgcn_s_barrier();
      __builtin_amdgcn_sched_barrier(0);
      bf16x8 af[4], bfr[4];
#pragma unroll
      for (int m = 0; m < 4; ++m)
        af[m] = *reinterpret_cast<const bf16x8*>(&Al[cur][kh][wm * 64 + m * 16 + lr][ch]);
#pragma unroll
      for (int n = 0; n < 4; ++n)
        bfr[n] = *reinterpret_cast<const bf16x8*>(&Bl[cur][kh][wn * 64 + n * 16 + lr][ch]);
      if (kh == 0) STG128(nxt, 0, kn); else STG128(nxt, 1, kn);
      __builtin_amdgcn_sched_barrier(0);
      __builtin_amdgcn_s_setprio(1);
#pragma unroll
      for (int m = 0; m < 4; ++m)
#pragma unroll
        for (int n = 0; n < 4; ++n)
          acc[m][n] = __builtin_amdgcn_mfma_f32_16x16x32_bf16(af[m], bfr[n], acc[m][n], 0, 0, 0);
      __builtin_amdgcn_s_setprio(0);
    }
  }
#undef STG128

  const int orow0 = rowBase + wm * 64 + g * 4;
  const int ocol0 = colBase + wn * 64 + lr;
  if constexpr (LORA) {
    float bl[4][8];
#pragma unroll
    for (int n = 0; n < 4; ++n) {
      const int cc = ocol0 + n * 16;
      const int fc = (cc < HID / 2) ? (2 * cc) : (2 * (cc - HID / 2) + 1);
#pragma unroll
      for (int e = 0; e < 8; ++e) bl[n][e] = BL[fc * LR + e];
    }
#pragma unroll
    for (int m = 0; m < 4; ++m) {
      float tr[4][8];
#pragma unroll
      for (int r2 = 0; r2 < 4; ++r2)
#pragma unroll
        for (int e = 0; e < 8; ++e) tr[r2][e] = T[(size_t)(orow0 + m * 16 + r2) * LR + e];
#pragma unroll
      for (int n = 0; n < 4; ++n)
#pragma unroll
        for (int r2 = 0; r2 < 4; ++r2) {
          float dot = 0.0f;
#pragma unroll
          for (int e = 0; e < 8; ++e) dot += tr[r2][e] * bl[n][e];
          outb[(size_t)(orow0 + m * 16 + r2) * HID + ocol0 + n * 16] =
              f2bf(acc[m][n][r2] + 2.0f * dot);
        }
    }
  } else {
#pragma unroll
    for (int m = 0; m < 4; ++m)
#pragma unroll
      for (int n = 0; n < 4; ++n)
#pragma unroll
        for (int r2 = 0; r2 < 4; ++r2)
          outf[(size_t)(orow0 + m * 16 + r2) * HID + ocol0 + n * 16] = acc[m][n][r2];
  }
}

// ---------------------------------------------------------------- causal flash attention v5
// R13 change vs v4: counted vmcnt. Old: STAGE(next); compute; vmcnt(0) [drains the
// JUST-issued prefetch]; barrier. New: STAGE(next); vmcnt(8) [waits only the
// 1-iteration-old loads of the tile about to be computed]; barrier; compute;
// barrier [WAR for next STAGE]. Last iteration drains fully (vmcnt(0)).
#define STAGE(buf_, kvb_)                                                                   \
  do {                                                                                      \
    _Pragma("unroll") for (int i_ = 0; i_ < 4; ++i_) {                                      \
      const int sb_ = (w * 4 + i_) * 64;                                                    \
      {                                                                                     \
        const int slot_ = sb_ + lane;                                                       \
        const int rr_ = slot_ >> 4, cc_ = slot_ & 15;                                       \
        __builtin_amdgcn_global_load_lds(                                                   \
            (glb_void*)(kg + (size_t)((kvb_) + rr_) * HID + h * HDIM +                      \
                        ((cc_ ^ (rr_ & 15)) << 3)),                                         \
            (lds_void*)(&Ks[buf_][sb_ * 8]), 16, 0, 0);                                     \
      }                                                                                     \
      {                                                                                     \
        const int slot_ = sb_ + lane;                                                       \
        const int rr_ = slot_ >> 3, cc_ = slot_ & 7;                                        \
        __builtin_amdgcn_global_load_lds(                                                   \
            (glb_void*)(vt + ((size_t)h * HDIM + rr_) * SEQ + (kvb_) +                      \
                        ((cc_ ^ (rr_ & 7)) << 3)),                                          \
            (lds_void*)(&Vs[buf_][sb_ * 8]), 16, 0, 0);                                     \
      }                                                                                     \
    }                                                                                       \
  } while (0)

__global__ __launch_bounds__(256, 2) void flash_attn5(const __hip_bfloat16* __restrict__ qg,
                                                      const __hip_bfloat16* __restrict__ kg,
                                                      const __hip_bfloat16* __restrict__ vt,
                                                      __hip_bfloat16* __restrict__ o) {
  __shared__ __hip_bfloat16 Ks[2][64 * 128];
  __shared__ __hip_bfloat16 Vs[2][128 * 64];
  const int tid = threadIdx.x;
  const int lane = tid & 63;
  const int w = tid >> 6;
  const int ql = lane & 31;
  const int hi = lane >> 5;
  const int bx = blockIdx.x;
  const int h = bx & 31;
  const int strip = (bx < 256) ? (bx >> 5) : (15 - ((bx - 256) >> 5));
  const float scale = 0.088388347648318447f;

  const int q0 = strip * 128 + w * 32;
  const int nt = 2 * strip + 2;
  const int qgl = q0 + ql;

  bf16x8 bq[8];
#pragma unroll
  for (int sl = 0; sl < 8; ++sl)
    bq[sl] = *reinterpret_cast<const bf16x8*>(qg + (size_t)qgl * HID + h * HDIM + sl * 16 + hi * 8);

  f32x16 accO[4];
#pragma unroll
  for (int db = 0; db < 4; ++db)
#pragma unroll
    for (int e = 0; e < 16; ++e) accO[db][e] = 0.0f;
  float m_run = -1e30f, lsum = 0.0f;

  int cur = 0;
  STAGE(0, 0);  // 8 outstanding per wave

  for (int t = 0; t < nt; ++t) {
    const int kvb = t * 64;
    if (t + 1 < nt) {
      STAGE(cur ^ 1, (t + 1) * 64);                    // 16 outstanding
      asm volatile("s_waitcnt vmcnt(8)" ::: "memory"); // retire THIS tile's loads
    } else {
      asm volatile("s_waitcnt vmcnt(0)" ::: "memory"); // last tile: full drain
    }
    __syncthreads();  // all waves' loads for `cur` visible
    if (kvb <= q0 + 31) {
      f32x16 sc[2];
#pragma unroll
      for (int sub = 0; sub < 2; ++sub) {
#pragma unroll
        for (int e = 0; e < 16; ++e) sc[sub][e] = 0.0f;
        const int krow = sub * 32 + ql;
#pragma unroll
        for (int sl = 0; sl < 8; ++sl) {
          const int chh = (sl * 2 + hi) ^ (ql & 15);
          bf16x8 ak = *reinterpret_cast<const bf16x8*>(&Ks[cur][krow * 128 + chh * 8]);
          sc[sub] = __builtin_amdgcn_mfma_f32_32x32x16_bf16(ak, bq[sl], sc[sub], 0, 0, 0);
        }
      }
      float smax = -3.0e38f;
      if (kvb + 63 > q0) {
#pragma unroll
        for (int sub = 0; sub < 2; ++sub)
#pragma unroll
          for (int r = 0; r < 16; ++r) {
            const int kvg = kvb + sub * 32 + (r & 3) + 8 * (r >> 2) + 4 * hi;
            float v2 = sc[sub][r] * scale;
            v2 = (kvg > qgl) ? -3.0e38f : v2;
            sc[sub][r] = v2;
            smax = fmaxf(smax, v2);
          }
      } else {
#pragma unroll
        for (int sub = 0; sub < 2; ++sub)
#pragma unroll
          for (int r = 0; r < 16; ++r) {
            const float v2 = sc[sub][r] * scale;
            sc[sub][r] = v2;
            smax = fmaxf(smax, v2);
          }
      }
      smax = fmaxf(smax, __shfl_xor(smax, 32));
      if (__any(smax > m_run + 8.0f)) {
        const float mnew = fmaxf(m_run, smax);
        const float sca = __expf(m_run - mnew);
        m_run = mnew;
        lsum *= sca;
#pragma unroll
        for (int r = 0; r < 16; ++r) {
          const float sr = __shfl(sca, (r & 3) + 8 * (r >> 2) + 4 * hi);
#pragma unroll
          for (int db = 0; db < 4; ++db) accO[db][r] *= sr;
        }
      }
      float psum = 0.0f;
#pragma unroll
      for (int sub = 0; sub < 2; ++sub)
#pragma unroll
        for (int r = 0; r < 16; ++r) {
          const float p = __expf(sc[sub][r] - m_run);
          sc[sub][r] = p;
          psum += p;
        }
      psum += __shfl_xor(psum, 32);
      lsum += psum;
      bf16x8 pa[4];
#pragma unroll
      for (int sub = 0; sub < 2; ++sub) {
        const unsigned A0 = pkbf(sc[sub][0], sc[sub][1]);
        const unsigned C0 = pkbf(sc[sub][2], sc[sub][3]);
        const unsigned B0 = pkbf(sc[sub][4], sc[sub][5]);
        const unsigned D0 = pkbf(sc[sub][6], sc[sub][7]);
        const unsigned A1 = pkbf(sc[sub][8], sc[sub][9]);
        const unsigned C1 = pkbf(sc[sub][10], sc[sub][11]);
        const unsigned B1 = pkbf(sc[sub][12], sc[sub][13]);
        const unsigned D1 = pkbf(sc[sub][14], sc[sub][15]);
        const unsigned sA0 = (unsigned)__shfl_xor((int)A0, 32);
        const unsigned sB0 = (unsigned)__shfl_xor((int)B0, 32);
        const unsigned sC0 = (unsigned)__shfl_xor((int)C0, 32);
        const unsigned sD0 = (unsigned)__shfl_xor((int)D0, 32);
        const unsigned sA1 = (unsigned)__shfl_xor((int)A1, 32);
        const unsigned sB1 = (unsigned)__shfl_xor((int)B1, 32);
        const unsigned sC1 = (unsigned)__shfl_xor((int)C1, 32);
        const unsigned sD1 = (unsigned)__shfl_xor((int)D1, 32);
        union { unsigned u[4]; bf16x8 v; } f0, f1;
        f0.u[0] = hi ? sB0 : A0;
        f0.u[1] = hi ? sD0 : C0;
        f0.u[2] = hi ? B0 : sA0;
        f0.u[3] = hi ? D0 : sC0;
        f1.u[0] = hi ? sB1 : A1;
        f1.u[1] = hi ? sD1 : C1;
        f1.u[2] = hi ? B1 : sA1;
        f1.u[3] = hi ? D1 : sC1;
        pa[sub * 2 + 0] = f0.v;
        pa[sub * 2 + 1] = f1.v;
      }
#pragma unroll
      for (int db = 0; db < 4; ++db) {
        const int vrow = db * 32 + ql;
#pragma unroll
        for (int ks = 0; ks < 4; ++ks) {
          const int chh = (ks * 2 + hi) ^ (ql & 7);
          bf16x8 bv = *reinterpret_cast<const bf16x8*>(&Vs[cur][vrow * 64 + chh * 8]);
          accO[db] = __builtin_amdgcn_mfma_f32_32x32x16_bf16(pa[ks], bv, accO[db], 0, 0, 0);
        }
      }
    }
    __syncthreads();  // WAR: next iter's STAGE overwrites `cur`
    cur ^= 1;
  }
  const float il = 1.0f / lsum;
#pragma unroll
  for (int r = 0; r < 16; ++r) {
    const int rb = (r & 3) + 8 * (r >> 2);
    const float ir = __shfl(il, rb + 4 * hi);
    const int qrow = q0 + rb + 4 * hi;
#pragma unroll
    for (int db = 0; db < 4; ++db)
      o[(size_t)qrow * HID + h * HDIM + db * 32 + ql] = f2bf(accO[db][r] * ir);
  }
}

// ----------------------------------------------------------------
extern "C" void kernel_launch(void* const* d_in, const int* in_sizes, int n_in,
                              void* d_out, int out_size, void* d_ws, size_t ws_size,
                              hipStream_t stream) {
  (void)in_sizes; (void)n_in; (void)out_size; (void)ws_size;
  const float* x  = (const float*)d_in[0];
  const float* Wq = (const float*)d_in[1];
  const float* Wk = (const float*)d_in[2];
  const float* Wv = (const float*)d_in[3];
  const float* Wo = (const float*)d_in[4];
  const float* Aq = (const float*)d_in[5];
  const float* Bq = (const float*)d_in[6];
  const float* Ak = (const float*)d_in[7];
  const float* Bk = (const float*)d_in[8];
  const float* Av = (const float*)d_in[9];
  const float* Bv = (const float*)d_in[10];
  float* out = (float*)d_out;

  char* p = (char*)d_ws;
  __hip_bfloat16* xb   = (__hip_bfloat16*)p; p += (size_t)SEQ * HID * 2;       // reused as ab
  __hip_bfloat16* wqkv = (__hip_bfloat16*)p; p += (size_t)3 * HID * HID * 2;   // [0:32M] reused for Wo
  __hip_bfloat16* qb   = (__hip_bfloat16*)p; p += (size_t)SEQ * HID * 2;
  __hip_bfloat16* kb   = (__hip_bfloat16*)p; p += (size_t)SEQ * HID * 2;
  __hip_bfloat16* vb   = (__hip_bfloat16*)p; p += (size_t)SEQ * HID * 2;
  __hip_bfloat16* vtb  = (__hip_bfloat16*)p; p += (size_t)SEQ * HID * 2;
  float* tq   = (float*)p; p += SEQ * LR * 4;
  float* tk   = (float*)p; p += SEQ * LR * 4;
  float* tv   = (float*)p; p += SEQ * LR * 4;
  float* cosb = (float*)p; p += SEQ * 64 * 4;
  float* sinb = (float*)p; p += SEQ * 64 * 4;
  __hip_bfloat16* ab = xb;  // x no longer needed after QKV GEMMs

  conv_f32_bf16<<<SEQ * HID / 1024, 256, 0, stream>>>(x, xb, SEQ * HID / 4);
  lora_t<<<SEQ * 3 / 4, 256, 0, stream>>>(x, Aq, Ak, Av, tq, tk, tv);
  rope_tables<<<SEQ * 64 / 256, 256, 0, stream>>>(cosb, sinb);
  conv_f32_bf16<<<HID * HID / 1024, 256, 0, stream>>>(Wq, wqkv + 0 * (size_t)HID * HID, HID * HID / 4);
  conv_f32_bf16<<<HID * HID / 1024, 256, 0, stream>>>(Wk, wqkv + 1 * (size_t)HID * HID, HID * HID / 4);
  conv_f32_bf16<<<HID * HID / 1024, 256, 0, stream>>>(Wv, wqkv + 2 * (size_t)HID * HID, HID * HID / 4);

  gemm128<true><<<dim3(32, 16, 3), 256, 0, stream>>>(xb, wqkv, tq, tk, tv, Bq, Bk, Bv,
                                                     qb, kb, vb, nullptr);

  rope_apply<<<SEQ * NHEADS * 64 / 256, 256, 0, stream>>>(qb, cosb, sinb);
  rope_apply<<<SEQ * NHEADS * 64 / 256, 256, 0, stream>>>(kb, cosb, sinb);
  transpose_v<<<dim3(SEQ / 64, HDIM / 64, NHEADS), 256, 0, stream>>>(vb, vtb);
  flash_attn5<<<512, 256, 0, stream>>>(qb, kb, vtb, ab);

  conv_f32_bf16<<<HID * HID / 1024, 256, 0, stream>>>(Wo, wqkv, HID * HID / 4);
  gemm128<false><<<dim3(32, 16, 1), 256, 0, stream>>>(ab, wqkv, nullptr, nullptr, nullptr,
                                                      nullptr, nullptr, nullptr,
                                                      nullptr, nullptr, nullptr, out);
}